// Round 1
// baseline (829.033 us; speedup 1.0000x reference)
//
#include <hip/hip_runtime.h>
#include <math.h>

#define BB 16
#define CC 256
#define C3 768
#define HH 56
#define WW 56
#define HWSZ 3136
#define HEADS 8
#define HD 32
#define EPSF 1e-12f

// ---------------------------------------------------------------------------
// GEMM: Y[z][m][n] = sum_k Wm[m][k] * X[z][k][n]
//   Wm: [M x 256] row-major (1x1 conv weights)
//   X : base + z*xStride, rows k at stride HWSZ
//   Y : base + z*yStride, rows m at stride HWSZ
//   grid: (N/64=49, M/64, z), block 256.  N=3136, K=256 exact -> no guards.
// ---------------------------------------------------------------------------
__global__ __launch_bounds__(256)
void gemm_k256(const float* __restrict__ Wm,
               const float* __restrict__ X,
               float* __restrict__ Y,
               long xStride, long yStride)
{
    __shared__ __align__(16) float As[16][68];
    __shared__ __align__(16) float Bs[16][68];
    const int tid = threadIdx.x;
    const int z = blockIdx.z;
    const float* Xb = X + (long)z * xStride;
    float* Yb = Y + (long)z * yStride;
    const int n0 = blockIdx.x * 64;
    const int m0 = blockIdx.y * 64;
    const int tr = tid >> 4, tc = tid & 15;

    float acc[4][4];
#pragma unroll
    for (int a = 0; a < 4; ++a)
#pragma unroll
        for (int b = 0; b < 4; ++b) acc[a][b] = 0.f;

    for (int k0 = 0; k0 < 256; k0 += 16) {
        // A tile: W[m0+r][k0+kk] -> As[kk][r]
#pragma unroll
        for (int l = 0; l < 4; ++l) {
            int idx = l * 256 + tid;
            int kk = idx & 15, r = idx >> 4;
            As[kk][r] = Wm[(long)(m0 + r) * 256 + (k0 + kk)];
        }
        // B tile: X[k0+kk][n0+c] -> Bs[kk][c]
#pragma unroll
        for (int l = 0; l < 4; ++l) {
            int idx = l * 256 + tid;
            int c = idx & 63, kk = idx >> 6;
            Bs[kk][c] = Xb[(long)(k0 + kk) * HWSZ + (n0 + c)];
        }
        __syncthreads();
#pragma unroll
        for (int k = 0; k < 16; ++k) {
            float4 a4 = *(const float4*)&As[k][tr * 4];
            float4 b4 = *(const float4*)&Bs[k][tc * 4];
            acc[0][0] += a4.x * b4.x; acc[0][1] += a4.x * b4.y;
            acc[0][2] += a4.x * b4.z; acc[0][3] += a4.x * b4.w;
            acc[1][0] += a4.y * b4.x; acc[1][1] += a4.y * b4.y;
            acc[1][2] += a4.y * b4.z; acc[1][3] += a4.y * b4.w;
            acc[2][0] += a4.z * b4.x; acc[2][1] += a4.z * b4.y;
            acc[2][2] += a4.z * b4.z; acc[2][3] += a4.z * b4.w;
            acc[3][0] += a4.w * b4.x; acc[3][1] += a4.w * b4.y;
            acc[3][2] += a4.w * b4.z; acc[3][3] += a4.w * b4.w;
        }
        __syncthreads();
    }
#pragma unroll
    for (int a = 0; a < 4; ++a) {
        float4 v = make_float4(acc[a][0], acc[a][1], acc[a][2], acc[a][3]);
        *(float4*)&Yb[(long)(m0 + tr * 4 + a) * HWSZ + (n0 + tc * 4)] = v;
    }
}

// ---------------------------------------------------------------------------
// Depthwise 3x3, pad 1.  X: tmp[z][ch][hw]; Y: dw[(b0+z)][ch][hw]
// grid: (13, 768, gcur), block 256.
// ---------------------------------------------------------------------------
__global__ __launch_bounds__(256)
void dwconv3x3(const float* __restrict__ X,
               const float* __restrict__ Wd,
               float* __restrict__ Y,
               int b0)
{
    const int p = blockIdx.x * 256 + threadIdx.x;
    if (p >= HWSZ) return;
    const int ch = blockIdx.y;
    const int z = blockIdx.z;
    const float* xc = X + ((long)z * C3 + ch) * HWSZ;
    float* yc = Y + ((long)(b0 + z) * C3 + ch) * HWSZ;
    const int i = p / WW, j = p % WW;
    const float* w = Wd + ch * 9;
    float s = 0.f;
#pragma unroll
    for (int di = 0; di < 3; ++di) {
        int ii = i + di - 1;
        if (ii < 0 || ii >= HH) continue;
#pragma unroll
        for (int dj = 0; dj < 3; ++dj) {
            int jj = j + dj - 1;
            if (jj < 0 || jj >= WW) continue;
            s += w[di * 3 + dj] * xc[ii * WW + jj];
        }
    }
    yc[p] = s;
}

// ---------------------------------------------------------------------------
// Attention scores: per (head, batch) block computes
//   attn[b,h,i,j] = softmax_j( (q_i . k_j) / (max(|q_i|,eps)*max(|k_j|,eps)) * T[h] )
// block 1024 threads, grid (8, 16).
// ---------------------------------------------------------------------------
__global__ __launch_bounds__(1024)
void attn_scores(const float* __restrict__ dw,
                 const float* __restrict__ temp,
                 float* __restrict__ attn)
{
    __shared__ __align__(16) float qs[32][66];
    __shared__ __align__(16) float ks[32][66];
    __shared__ float nrm[64];
    const int h = blockIdx.x, b = blockIdx.y;
    const int t = threadIdx.x;
    const float* qb = dw + ((long)b * C3 + h * HD) * HWSZ;
    const float* kb = dw + ((long)b * C3 + CC + h * HD) * HWSZ;

    // row L2 norms: 16 threads per row, 64 rows (32 q + 32 k)
    {
        const int r = t >> 4;
        const int l = t & 15;
        const float* row = (r < 32) ? (qb + (long)r * HWSZ) : (kb + (long)(r - 32) * HWSZ);
        float s = 0.f;
        for (int p = l; p < HWSZ; p += 16) { float v = row[p]; s += v * v; }
        s += __shfl_xor(s, 1); s += __shfl_xor(s, 2);
        s += __shfl_xor(s, 4); s += __shfl_xor(s, 8);
        if (l == 0) nrm[r] = fmaxf(sqrtf(s), EPSF);
    }
    __syncthreads();

    const int i = t >> 5, j = t & 31;
    float acc = 0.f;
    const int lr = t >> 5;            // 0..31
    const int lc = (t & 31) * 2;      // 0..62 even
    for (int k0 = 0; k0 < HWSZ; k0 += 64) {
        *(float2*)&qs[lr][lc] = *(const float2*)&qb[(long)lr * HWSZ + k0 + lc];
        *(float2*)&ks[lr][lc] = *(const float2*)&kb[(long)lr * HWSZ + k0 + lc];
        __syncthreads();
#pragma unroll
        for (int p = 0; p < 64; ++p) acc += qs[i][p] * ks[j][p];
        __syncthreads();
    }

    float s = acc * (temp[h] / (nrm[i] * nrm[32 + j]));
    // softmax over j (low 5 lane bits)
    float mx = s;
    mx = fmaxf(mx, __shfl_xor(mx, 1));
    mx = fmaxf(mx, __shfl_xor(mx, 2));
    mx = fmaxf(mx, __shfl_xor(mx, 4));
    mx = fmaxf(mx, __shfl_xor(mx, 8));
    mx = fmaxf(mx, __shfl_xor(mx, 16));
    float e = expf(s - mx);
    float sum = e;
    sum += __shfl_xor(sum, 1); sum += __shfl_xor(sum, 2);
    sum += __shfl_xor(sum, 4); sum += __shfl_xor(sum, 8);
    sum += __shfl_xor(sum, 16);
    attn[(((long)b * HEADS + h) * HD + i) * HD + j] = e / sum;
}

// ---------------------------------------------------------------------------
// out[b, h*32+i, p] = sum_j attn[b,h,i,j] * v[b,h,j,p]
// writes into the (dead) q-channel section of dw. grid (13, 8, 16), block 256.
// ---------------------------------------------------------------------------
__global__ __launch_bounds__(256)
void attn_apply(float* __restrict__ dw,
                const float* __restrict__ attn)
{
    __shared__ float As[HD * HD];
    const int h = blockIdx.y, b = blockIdx.z;
    const int t = threadIdx.x;
    const float* ab = attn + ((long)b * HEADS + h) * HD * HD;
#pragma unroll
    for (int l = 0; l < 4; ++l) As[l * 256 + t] = ab[l * 256 + t];
    __syncthreads();
    const int p = blockIdx.x * 256 + t;
    if (p >= HWSZ) return;
    const float* vb = dw + ((long)b * C3 + 2 * CC + h * HD) * HWSZ;
    float* ob = dw + ((long)b * C3 + h * HD) * HWSZ;
    float acc[32];
#pragma unroll
    for (int i = 0; i < 32; ++i) acc[i] = 0.f;
    for (int j = 0; j < 32; ++j) {
        float vv = vb[(long)j * HWSZ + p];
#pragma unroll
        for (int i = 0; i < 32; ++i) acc[i] += As[i * 32 + j] * vv;
    }
#pragma unroll
    for (int i = 0; i < 32; ++i) ob[(long)i * HWSZ + p] = acc[i];
}

// ---------------------------------------------------------------------------
extern "C" void kernel_launch(void* const* d_in, const int* in_sizes, int n_in,
                              void* d_out, int out_size, void* d_ws, size_t ws_size,
                              hipStream_t stream)
{
    const float* x      = (const float*)d_in[0];
    const float* w_qkv  = (const float*)d_in[1];
    const float* w_dw   = (const float*)d_in[2];
    const float* w_proj = (const float*)d_in[3];
    const float* temp   = (const float*)d_in[4];
    float* out = (float*)d_out;
    float* ws  = (float*)d_ws;

    const size_t dwF = (size_t)BB * C3 * HWSZ;          // 38,535,168 floats
    const size_t atF = (size_t)BB * HEADS * HD * HD;    // 131,072 floats
    const size_t pbF = (size_t)C3 * HWSZ;               // per-batch qkv tmp

    float* dw  = ws;
    float* at  = ws + dwF;
    float* tmp = ws + dwF + atF;

    // batch-group size that fits in the workspace (deterministic in ws_size)
    long availF = (long)(ws_size / 4) - (long)(dwF + atF);
    long gl = availF / (long)pbF;
    if (gl < 1) gl = 1;
    if (gl > BB) gl = BB;
    const int g = (int)gl;

    for (int b0 = 0; b0 < BB; b0 += g) {
        int gc = g < (BB - b0) ? g : (BB - b0);
        gemm_k256<<<dim3(49, 12, gc), 256, 0, stream>>>(
            w_qkv, x + (size_t)b0 * CC * HWSZ, tmp,
            (long)CC * HWSZ, (long)C3 * HWSZ);
        dwconv3x3<<<dim3(13, C3, gc), 256, 0, stream>>>(tmp, w_dw, dw, b0);
    }
    attn_scores<<<dim3(HEADS, BB), 1024, 0, stream>>>(dw, temp, at);
    attn_apply<<<dim3(13, HEADS, BB), 256, 0, stream>>>(dw, at);
    gemm_k256<<<dim3(49, 4, BB), 256, 0, stream>>>(
        w_proj, dw, out, (long)C3 * HWSZ, (long)CC * HWSZ);
}

// Round 2
// 666.237 us; speedup vs baseline: 1.2444x; 1.2444x over previous
//
#include <hip/hip_runtime.h>
#include <math.h>

#define BB 16
#define CC 256
#define C3 768
#define HH 56
#define WW 56
#define HWSZ 3136
#define HEADS 8
#define HD 32
#define EPSF 1e-12f
#define NCHUNK 7
#define CPX (HWSZ / NCHUNK)   // 448
#define SLAB 1088             // 32*32 gram + 32 q-sumsq + 32 k-sumsq

// ---------------------------------------------------------------------------
// GEMM: Y[z][m][n] = sum_k Wm[m][k] * X[z][k][n]
//   grid: (49, M/64, z), block 256. N=3136, K=256 exact -> no guards.
// ---------------------------------------------------------------------------
__global__ __launch_bounds__(256)
void gemm_k256(const float* __restrict__ Wm,
               const float* __restrict__ X,
               float* __restrict__ Y,
               long xStride, long yStride)
{
    __shared__ __align__(16) float As[16][68];
    __shared__ __align__(16) float Bs[16][68];
    const int tid = threadIdx.x;
    const int z = blockIdx.z;
    const float* Xb = X + (long)z * xStride;
    float* Yb = Y + (long)z * yStride;
    const int n0 = blockIdx.x * 64;
    const int m0 = blockIdx.y * 64;
    const int tr = tid >> 4, tc = tid & 15;

    float acc[4][4];
#pragma unroll
    for (int a = 0; a < 4; ++a)
#pragma unroll
        for (int b = 0; b < 4; ++b) acc[a][b] = 0.f;

    for (int k0 = 0; k0 < 256; k0 += 16) {
#pragma unroll
        for (int l = 0; l < 4; ++l) {
            int idx = l * 256 + tid;
            int kk = idx & 15, r = idx >> 4;
            As[kk][r] = Wm[(long)(m0 + r) * 256 + (k0 + kk)];
        }
#pragma unroll
        for (int l = 0; l < 4; ++l) {
            int idx = l * 256 + tid;
            int c = idx & 63, kk = idx >> 6;
            Bs[kk][c] = Xb[(long)(k0 + kk) * HWSZ + (n0 + c)];
        }
        __syncthreads();
#pragma unroll
        for (int k = 0; k < 16; ++k) {
            float4 a4 = *(const float4*)&As[k][tr * 4];
            float4 b4 = *(const float4*)&Bs[k][tc * 4];
            acc[0][0] += a4.x * b4.x; acc[0][1] += a4.x * b4.y;
            acc[0][2] += a4.x * b4.z; acc[0][3] += a4.x * b4.w;
            acc[1][0] += a4.y * b4.x; acc[1][1] += a4.y * b4.y;
            acc[1][2] += a4.y * b4.z; acc[1][3] += a4.y * b4.w;
            acc[2][0] += a4.z * b4.x; acc[2][1] += a4.z * b4.y;
            acc[2][2] += a4.z * b4.z; acc[2][3] += a4.z * b4.w;
            acc[3][0] += a4.w * b4.x; acc[3][1] += a4.w * b4.y;
            acc[3][2] += a4.w * b4.z; acc[3][3] += a4.w * b4.w;
        }
        __syncthreads();
    }
#pragma unroll
    for (int a = 0; a < 4; ++a) {
        float4 v = make_float4(acc[a][0], acc[a][1], acc[a][2], acc[a][3]);
        *(float4*)&Yb[(long)(m0 + tr * 4 + a) * HWSZ + (n0 + tc * 4)] = v;
    }
}

// ---------------------------------------------------------------------------
// Depthwise 3x3, pad 1.
// ---------------------------------------------------------------------------
__global__ __launch_bounds__(256)
void dwconv3x3(const float* __restrict__ X,
               const float* __restrict__ Wd,
               float* __restrict__ Y,
               int b0)
{
    const int p = blockIdx.x * 256 + threadIdx.x;
    if (p >= HWSZ) return;
    const int ch = blockIdx.y;
    const int z = blockIdx.z;
    const float* xc = X + ((long)z * C3 + ch) * HWSZ;
    float* yc = Y + ((long)(b0 + z) * C3 + ch) * HWSZ;
    const int i = p / WW, j = p % WW;
    const float* w = Wd + ch * 9;
    float s = 0.f;
#pragma unroll
    for (int di = 0; di < 3; ++di) {
        int ii = i + di - 1;
        if (ii < 0 || ii >= HH) continue;
#pragma unroll
        for (int dj = 0; dj < 3; ++dj) {
            int jj = j + dj - 1;
            if (jj < 0 || jj >= WW) continue;
            s += w[di * 3 + dj] * xc[ii * WW + jj];
        }
    }
    yc[p] = s;
}

// ---------------------------------------------------------------------------
// Phase A: partial Gram. Each block: 448 pixels of one (b,h); computes
// partial S[32][32] = sum_p q_i[p]*k_j[p] plus per-row sumsq of q and k.
// grid (7, 8, 16), block 256. Writes its own slab -> deterministic, no atomics.
// ---------------------------------------------------------------------------
__global__ __launch_bounds__(256)
void gram_partial(const float* __restrict__ dw, float* __restrict__ gram)
{
    __shared__ __align__(16) float qT[64][34];   // pixel-major (transposed)
    __shared__ __align__(16) float kT[64][34];
    const int c = blockIdx.x, h = blockIdx.y, b = blockIdx.z;
    const int t = threadIdx.x;
    const float* qb = dw + ((long)b * C3 + h * HD) * HWSZ;
    const float* kb = dw + ((long)b * C3 + CC + h * HD) * HWSZ;
    const int r  = t >> 3;          // 0..31 : row this thread loads
    const int pl = (t & 7) * 8;     // 8 pixels within the 64-pixel tile
    const int i2 = (t >> 4) * 2;    // 0..30 even : acc rows
    const int j2 = (t & 15) * 2;    // 0..30 even : acc cols

    float a00 = 0.f, a01 = 0.f, a10 = 0.f, a11 = 0.f;
    float qss = 0.f, kss = 0.f;
    const int base = c * CPX;

    for (int t0 = 0; t0 < CPX; t0 += 64) {
        const float* qp = &qb[(long)r * HWSZ + base + t0 + pl];
        const float* kp = &kb[(long)r * HWSZ + base + t0 + pl];
        float4 qa = *(const float4*)qp;
        float4 qc = *(const float4*)(qp + 4);
        float4 ka = *(const float4*)kp;
        float4 kc = *(const float4*)(kp + 4);
        qss += qa.x*qa.x + qa.y*qa.y + qa.z*qa.z + qa.w*qa.w
             + qc.x*qc.x + qc.y*qc.y + qc.z*qc.z + qc.w*qc.w;
        kss += ka.x*ka.x + ka.y*ka.y + ka.z*ka.z + ka.w*ka.w
             + kc.x*kc.x + kc.y*kc.y + kc.z*kc.z + kc.w*kc.w;
        qT[pl+0][r] = qa.x; qT[pl+1][r] = qa.y; qT[pl+2][r] = qa.z; qT[pl+3][r] = qa.w;
        qT[pl+4][r] = qc.x; qT[pl+5][r] = qc.y; qT[pl+6][r] = qc.z; qT[pl+7][r] = qc.w;
        kT[pl+0][r] = ka.x; kT[pl+1][r] = ka.y; kT[pl+2][r] = ka.z; kT[pl+3][r] = ka.w;
        kT[pl+4][r] = kc.x; kT[pl+5][r] = kc.y; kT[pl+6][r] = kc.z; kT[pl+7][r] = kc.w;
        __syncthreads();
#pragma unroll
        for (int p = 0; p < 64; ++p) {
            float2 q2 = *(const float2*)&qT[p][i2];
            float2 k2 = *(const float2*)&kT[p][j2];
            a00 += q2.x * k2.x; a01 += q2.x * k2.y;
            a10 += q2.y * k2.x; a11 += q2.y * k2.y;
        }
        __syncthreads();
    }

    float* slab = gram + (((long)c * BB + b) * HEADS + h) * SLAB;
    slab[(i2+0) * 32 + j2+0] = a00;
    slab[(i2+0) * 32 + j2+1] = a01;
    slab[(i2+1) * 32 + j2+0] = a10;
    slab[(i2+1) * 32 + j2+1] = a11;
    // reduce row sumsq across the 8 lanes sharing row r (consecutive lanes)
    qss += __shfl_xor(qss, 1); qss += __shfl_xor(qss, 2); qss += __shfl_xor(qss, 4);
    kss += __shfl_xor(kss, 1); kss += __shfl_xor(kss, 2); kss += __shfl_xor(kss, 4);
    if ((t & 7) == 0) { slab[1024 + r] = qss; slab[1056 + r] = kss; }
}

// ---------------------------------------------------------------------------
// Phase B: sum chunk slabs, normalize, temperature, softmax over j.
// grid (8, 16), block 1024.
// ---------------------------------------------------------------------------
__global__ __launch_bounds__(1024)
void attn_finish(const float* __restrict__ gram,
                 const float* __restrict__ temp,
                 float* __restrict__ attn)
{
    __shared__ float nrm[64];
    const int h = blockIdx.x, b = blockIdx.y;
    const int t = threadIdx.x;
    const long sbase = ((long)b * HEADS + h) * SLAB;
    const long cstr  = (long)BB * HEADS * SLAB;
    if (t < 64) {
        float s = 0.f;
#pragma unroll
        for (int c = 0; c < NCHUNK; ++c) s += gram[c * cstr + sbase + 1024 + t];
        nrm[t] = fmaxf(sqrtf(s), EPSF);
    }
    __syncthreads();
    const int i = t >> 5, j = t & 31;
    float s = 0.f;
#pragma unroll
    for (int c = 0; c < NCHUNK; ++c) s += gram[c * cstr + sbase + i * 32 + j];
    s *= temp[h] / (nrm[i] * nrm[32 + j]);
    float mx = s;
    mx = fmaxf(mx, __shfl_xor(mx, 1));
    mx = fmaxf(mx, __shfl_xor(mx, 2));
    mx = fmaxf(mx, __shfl_xor(mx, 4));
    mx = fmaxf(mx, __shfl_xor(mx, 8));
    mx = fmaxf(mx, __shfl_xor(mx, 16));
    float e = expf(s - mx);
    float sum = e;
    sum += __shfl_xor(sum, 1); sum += __shfl_xor(sum, 2);
    sum += __shfl_xor(sum, 4); sum += __shfl_xor(sum, 8);
    sum += __shfl_xor(sum, 16);
    attn[(((long)b * HEADS + h) * HD + i) * HD + j] = e / sum;
}

// ---------------------------------------------------------------------------
// out[b, h*32+i, p] = sum_j attn[b,h,i,j] * v[b,h,j,p]  (into dead q section)
// ---------------------------------------------------------------------------
__global__ __launch_bounds__(256)
void attn_apply(float* __restrict__ dw,
                const float* __restrict__ attn)
{
    __shared__ float As[HD * HD];
    const int h = blockIdx.y, b = blockIdx.z;
    const int t = threadIdx.x;
    const float* ab = attn + ((long)b * HEADS + h) * HD * HD;
#pragma unroll
    for (int l = 0; l < 4; ++l) As[l * 256 + t] = ab[l * 256 + t];
    __syncthreads();
    const int p = blockIdx.x * 256 + t;
    if (p >= HWSZ) return;
    const float* vb = dw + ((long)b * C3 + 2 * CC + h * HD) * HWSZ;
    float* ob = dw + ((long)b * C3 + h * HD) * HWSZ;
    float acc[32];
#pragma unroll
    for (int i = 0; i < 32; ++i) acc[i] = 0.f;
    for (int j = 0; j < 32; ++j) {
        float vv = vb[(long)j * HWSZ + p];
#pragma unroll
        for (int i = 0; i < 32; ++i) acc[i] += As[i * 32 + j] * vv;
    }
#pragma unroll
    for (int i = 0; i < 32; ++i) ob[(long)i * HWSZ + p] = acc[i];
}

// ---------------------------------------------------------------------------
extern "C" void kernel_launch(void* const* d_in, const int* in_sizes, int n_in,
                              void* d_out, int out_size, void* d_ws, size_t ws_size,
                              hipStream_t stream)
{
    const float* x      = (const float*)d_in[0];
    const float* w_qkv  = (const float*)d_in[1];
    const float* w_dw   = (const float*)d_in[2];
    const float* w_proj = (const float*)d_in[3];
    const float* temp   = (const float*)d_in[4];
    float* out = (float*)d_out;
    float* ws  = (float*)d_ws;

    const size_t dwF = (size_t)BB * C3 * HWSZ;                    // 38.5M floats
    const size_t atF = (size_t)BB * HEADS * HD * HD;              // 131k floats
    const size_t grF = (size_t)NCHUNK * BB * HEADS * SLAB;        // 975k floats
    const size_t pbF = (size_t)C3 * HWSZ;                         // per-batch tmp

    float* dw   = ws;
    float* at   = ws + dwF;
    float* gram = ws + dwF + atF;
    float* tmp  = ws + dwF + atF + grF;

    long availF = (long)(ws_size / 4) - (long)(dwF + atF + grF);
    long gl = availF / (long)pbF;
    if (gl < 1) gl = 1;
    if (gl > BB) gl = BB;
    const int g = (int)gl;

    for (int b0 = 0; b0 < BB; b0 += g) {
        int gc = g < (BB - b0) ? g : (BB - b0);
        gemm_k256<<<dim3(49, 12, gc), 256, 0, stream>>>(
            w_qkv, x + (size_t)b0 * CC * HWSZ, tmp,
            (long)CC * HWSZ, (long)C3 * HWSZ);
        dwconv3x3<<<dim3(13, C3, gc), 256, 0, stream>>>(tmp, w_dw, dw, b0);
    }
    gram_partial<<<dim3(NCHUNK, HEADS, BB), 256, 0, stream>>>(dw, gram);
    attn_finish<<<dim3(HEADS, BB), 1024, 0, stream>>>(gram, temp, at);
    attn_apply<<<dim3(13, HEADS, BB), 256, 0, stream>>>(dw, at);
    gemm_k256<<<dim3(49, 4, BB), 256, 0, stream>>>(
        w_proj, dw, out, (long)C3 * HWSZ, (long)CC * HWSZ);
}

// Round 3
// 404.909 us; speedup vs baseline: 2.0475x; 1.6454x over previous
//
#include <hip/hip_runtime.h>
#include <math.h>

#define BB 16
#define CC 256
#define C3 768
#define HH 56
#define WW 56
#define HWSZ 3136
#define HEADS 8
#define HD 32
#define EPSF 1e-12f
#define NCHUNK 7
#define CPX (HWSZ / NCHUNK)   // 448
#define SLAB 1088             // 32*32 gram + 32 q-sumsq + 32 k-sumsq

using s16x8 = __attribute__((ext_vector_type(8))) short;
using u16x8 = __attribute__((ext_vector_type(8))) unsigned short;
using f32x4 = __attribute__((ext_vector_type(4))) float;

__device__ inline unsigned short f2bf(float f) {
    unsigned int u = __float_as_uint(f);
    return (unsigned short)((u + 0x7FFFu + ((u >> 16) & 1u)) >> 16);
}

// ---------------------------------------------------------------------------
// Convert + transpose: x fp32 [256][3136] -> xbT bf16 [3136][256] (per batch).
// grid (49, 4, BB), block 256. 64x64 tiles through LDS.
// ---------------------------------------------------------------------------
__global__ __launch_bounds__(256)
void cvt_x_T(const float* __restrict__ X, unsigned short* __restrict__ XT)
{
    __shared__ float L[64][65];
    const int t = threadIdx.x;
    const int n0 = blockIdx.x * 64;
    const int c0 = blockIdx.y * 64;
    const long bofX = (long)blockIdx.z * CC * HWSZ;
    const long bofT = (long)blockIdx.z * HWSZ * CC;
#pragma unroll
    for (int l = 0; l < 4; ++l) {
        int idx = l * 256 + t;
        int ch = idx >> 4, n4 = (idx & 15) * 4;
        float4 v = *(const float4*)&X[bofX + (long)(c0 + ch) * HWSZ + n0 + n4];
        L[n4 + 0][ch] = v.x; L[n4 + 1][ch] = v.y;
        L[n4 + 2][ch] = v.z; L[n4 + 3][ch] = v.w;
    }
    __syncthreads();
#pragma unroll
    for (int l = 0; l < 2; ++l) {
        int idx = l * 256 + t;
        int r = idx >> 3, c8 = (idx & 7) * 8;
        u16x8 o;
#pragma unroll
        for (int e = 0; e < 8; ++e) o[e] = f2bf(L[r][c8 + e]);
        *(u16x8*)&XT[bofT + (long)(n0 + r) * CC + c0 + c8] = o;
    }
}

// ---------------------------------------------------------------------------
// fp32 -> bf16 flat convert (weights). n multiple of 2048; grid n/2048.
// ---------------------------------------------------------------------------
__global__ __launch_bounds__(256)
void cvt_w(const float* __restrict__ A, unsigned short* __restrict__ B)
{
    int i = (blockIdx.x * 256 + threadIdx.x) * 8;
    float4 a = *(const float4*)&A[i];
    float4 b = *(const float4*)&A[i + 4];
    u16x8 o;
    o[0] = f2bf(a.x); o[1] = f2bf(a.y); o[2] = f2bf(a.z); o[3] = f2bf(a.w);
    o[4] = f2bf(b.x); o[5] = f2bf(b.y); o[6] = f2bf(b.z); o[7] = f2bf(b.w);
    *(u16x8*)&B[i] = o;
}

// ---------------------------------------------------------------------------
// MFMA GEMM: Y[z][m][n] = sum_k W[m][k] * X[z][n][k]   (X is n-major bf16)
// tile 128m x 64n, 4 waves (each 64m x 32n), K=256 in 8 steps of 32.
// grid (49, M/128, z), block 256.
// ---------------------------------------------------------------------------
__global__ __launch_bounds__(256)
void gemm_mfma(const unsigned short* __restrict__ Wb,
               const unsigned short* __restrict__ XT,
               float* __restrict__ Y,
               long xStride, long yStride)
{
    __shared__ __align__(16) unsigned short As[128][40];
    __shared__ __align__(16) unsigned short Bs[64][40];
    const int t = threadIdx.x;
    const int z = blockIdx.z;
    const unsigned short* Xb = XT + (long)z * xStride;
    float* Yb = Y + (long)z * yStride;
    const int n0 = blockIdx.x * 64;
    const int m0 = blockIdx.y * 128;

    const int w = t >> 6, lane = t & 63;
    const int m_off = (w >> 1) * 64, n_off = (w & 1) * 32;
    const int lr = lane & 15, lk = (lane >> 4) * 8;

    f32x4 acc[4][2];
#pragma unroll
    for (int i = 0; i < 4; ++i)
#pragma unroll
        for (int j = 0; j < 2; ++j) acc[i][j] = (f32x4){0.f, 0.f, 0.f, 0.f};

    const int am = t >> 2, akc = (t & 3) * 8;          // A-stage: rows t>>2, +128 on l=1
    const int bn = t >> 2, bkc = (t & 3) * 8;          // B-stage

    for (int k0 = 0; k0 < 256; k0 += 32) {
        *(u16x8*)&As[am][akc] =
            *(const u16x8*)&Wb[(long)(m0 + am) * 256 + k0 + akc];
        *(u16x8*)&As[64 + am][akc] =
            *(const u16x8*)&Wb[(long)(m0 + 64 + am) * 256 + k0 + akc];
        *(u16x8*)&Bs[bn][bkc] =
            *(const u16x8*)&Xb[(long)(n0 + bn) * 256 + k0 + bkc];
        __syncthreads();
        s16x8 af[4], bf[2];
#pragma unroll
        for (int i = 0; i < 4; ++i)
            af[i] = *(const s16x8*)&As[m_off + i * 16 + lr][lk];
#pragma unroll
        for (int j = 0; j < 2; ++j)
            bf[j] = *(const s16x8*)&Bs[n_off + j * 16 + lr][lk];
#pragma unroll
        for (int i = 0; i < 4; ++i)
#pragma unroll
            for (int j = 0; j < 2; ++j)
                acc[i][j] = __builtin_amdgcn_mfma_f32_16x16x32_bf16(
                    af[i], bf[j], acc[i][j], 0, 0, 0);
        __syncthreads();
    }
    const int orow = (lane >> 4) * 4, ocol = lane & 15;
#pragma unroll
    for (int i = 0; i < 4; ++i)
#pragma unroll
        for (int j = 0; j < 2; ++j)
#pragma unroll
            for (int r = 0; r < 4; ++r)
                Yb[(long)(m0 + m_off + i * 16 + orow + r) * HWSZ
                   + n0 + n_off + j * 16 + ocol] = acc[i][j][r];
}

// ---------------------------------------------------------------------------
// Depthwise 3x3, pad 1.
// ---------------------------------------------------------------------------
__global__ __launch_bounds__(256)
void dwconv3x3(const float* __restrict__ X,
               const float* __restrict__ Wd,
               float* __restrict__ Y,
               int b0)
{
    const int p = blockIdx.x * 256 + threadIdx.x;
    if (p >= HWSZ) return;
    const int ch = blockIdx.y;
    const int z = blockIdx.z;
    const float* xc = X + ((long)z * C3 + ch) * HWSZ;
    float* yc = Y + ((long)(b0 + z) * C3 + ch) * HWSZ;
    const int i = p / WW, j = p % WW;
    const float* w = Wd + ch * 9;
    float s = 0.f;
#pragma unroll
    for (int di = 0; di < 3; ++di) {
        int ii = i + di - 1;
        if (ii < 0 || ii >= HH) continue;
#pragma unroll
        for (int dj = 0; dj < 3; ++dj) {
            int jj = j + dj - 1;
            if (jj < 0 || jj >= WW) continue;
            s += w[di * 3 + dj] * xc[ii * WW + jj];
        }
    }
    yc[p] = s;
}

// ---------------------------------------------------------------------------
// Phase A: partial Gram (448 px per block). grid (7, 8, 16), block 256.
// ---------------------------------------------------------------------------
__global__ __launch_bounds__(256)
void gram_partial(const float* __restrict__ dw, float* __restrict__ gram)
{
    __shared__ __align__(16) float qT[64][34];
    __shared__ __align__(16) float kT[64][34];
    const int c = blockIdx.x, h = blockIdx.y, b = blockIdx.z;
    const int t = threadIdx.x;
    const float* qb = dw + ((long)b * C3 + h * HD) * HWSZ;
    const float* kb = dw + ((long)b * C3 + CC + h * HD) * HWSZ;
    const int r  = t >> 3;
    const int pl = (t & 7) * 8;
    const int i2 = (t >> 4) * 2;
    const int j2 = (t & 15) * 2;

    float a00 = 0.f, a01 = 0.f, a10 = 0.f, a11 = 0.f;
    float qss = 0.f, kss = 0.f;
    const int base = c * CPX;

    for (int t0 = 0; t0 < CPX; t0 += 64) {
        const float* qp = &qb[(long)r * HWSZ + base + t0 + pl];
        const float* kp = &kb[(long)r * HWSZ + base + t0 + pl];
        float4 qa = *(const float4*)qp;
        float4 qc = *(const float4*)(qp + 4);
        float4 ka = *(const float4*)kp;
        float4 kc = *(const float4*)(kp + 4);
        qss += qa.x*qa.x + qa.y*qa.y + qa.z*qa.z + qa.w*qa.w
             + qc.x*qc.x + qc.y*qc.y + qc.z*qc.z + qc.w*qc.w;
        kss += ka.x*ka.x + ka.y*ka.y + ka.z*ka.z + ka.w*ka.w
             + kc.x*kc.x + kc.y*kc.y + kc.z*kc.z + kc.w*kc.w;
        qT[pl+0][r] = qa.x; qT[pl+1][r] = qa.y; qT[pl+2][r] = qa.z; qT[pl+3][r] = qa.w;
        qT[pl+4][r] = qc.x; qT[pl+5][r] = qc.y; qT[pl+6][r] = qc.z; qT[pl+7][r] = qc.w;
        kT[pl+0][r] = ka.x; kT[pl+1][r] = ka.y; kT[pl+2][r] = ka.z; kT[pl+3][r] = ka.w;
        kT[pl+4][r] = kc.x; kT[pl+5][r] = kc.y; kT[pl+6][r] = kc.z; kT[pl+7][r] = kc.w;
        __syncthreads();
#pragma unroll
        for (int p = 0; p < 64; ++p) {
            float2 q2 = *(const float2*)&qT[p][i2];
            float2 k2 = *(const float2*)&kT[p][j2];
            a00 += q2.x * k2.x; a01 += q2.x * k2.y;
            a10 += q2.y * k2.x; a11 += q2.y * k2.y;
        }
        __syncthreads();
    }

    float* slab = gram + (((long)c * BB + b) * HEADS + h) * SLAB;
    slab[(i2+0) * 32 + j2+0] = a00;
    slab[(i2+0) * 32 + j2+1] = a01;
    slab[(i2+1) * 32 + j2+0] = a10;
    slab[(i2+1) * 32 + j2+1] = a11;
    qss += __shfl_xor(qss, 1); qss += __shfl_xor(qss, 2); qss += __shfl_xor(qss, 4);
    kss += __shfl_xor(kss, 1); kss += __shfl_xor(kss, 2); kss += __shfl_xor(kss, 4);
    if ((t & 7) == 0) { slab[1024 + r] = qss; slab[1056 + r] = kss; }
}

// ---------------------------------------------------------------------------
// Phase B: sum slabs, normalize, temperature, softmax over j. grid (8,16).
// ---------------------------------------------------------------------------
__global__ __launch_bounds__(1024)
void attn_finish(const float* __restrict__ gram,
                 const float* __restrict__ temp,
                 float* __restrict__ attn)
{
    __shared__ float nrm[64];
    const int h = blockIdx.x, b = blockIdx.y;
    const int t = threadIdx.x;
    const long sbase = ((long)b * HEADS + h) * SLAB;
    const long cstr  = (long)BB * HEADS * SLAB;
    if (t < 64) {
        float s = 0.f;
#pragma unroll
        for (int c = 0; c < NCHUNK; ++c) s += gram[c * cstr + sbase + 1024 + t];
        nrm[t] = fmaxf(sqrtf(s), EPSF);
    }
    __syncthreads();
    const int i = t >> 5, j = t & 31;
    float s = 0.f;
#pragma unroll
    for (int c = 0; c < NCHUNK; ++c) s += gram[c * cstr + sbase + i * 32 + j];
    s *= temp[h] / (nrm[i] * nrm[32 + j]);
    float mx = s;
    mx = fmaxf(mx, __shfl_xor(mx, 1));
    mx = fmaxf(mx, __shfl_xor(mx, 2));
    mx = fmaxf(mx, __shfl_xor(mx, 4));
    mx = fmaxf(mx, __shfl_xor(mx, 8));
    mx = fmaxf(mx, __shfl_xor(mx, 16));
    float e = expf(s - mx);
    float sum = e;
    sum += __shfl_xor(sum, 1); sum += __shfl_xor(sum, 2);
    sum += __shfl_xor(sum, 4); sum += __shfl_xor(sum, 8);
    sum += __shfl_xor(sum, 16);
    attn[(((long)b * HEADS + h) * HD + i) * HD + j] = e / sum;
}

// ---------------------------------------------------------------------------
// out[b, p, h*32+i] (bf16, n-major for proj GEMM) = sum_j attn * v[b,h,j,p]
// grid (13, 8, 16), block 256.
// ---------------------------------------------------------------------------
__global__ __launch_bounds__(256)
void attn_apply(const float* __restrict__ dw,
                const float* __restrict__ attn,
                unsigned short* __restrict__ obT)
{
    __shared__ float As[HD * HD];
    const int h = blockIdx.y, b = blockIdx.z;
    const int t = threadIdx.x;
    const float* ab = attn + ((long)b * HEADS + h) * HD * HD;
#pragma unroll
    for (int l = 0; l < 4; ++l) As[l * 256 + t] = ab[l * 256 + t];
    __syncthreads();
    const int p = blockIdx.x * 256 + t;
    if (p >= HWSZ) return;
    const float* vb = dw + ((long)b * C3 + 2 * CC + h * HD) * HWSZ;
    float acc[32];
#pragma unroll
    for (int i = 0; i < 32; ++i) acc[i] = 0.f;
    for (int j = 0; j < 32; ++j) {
        float vv = vb[(long)j * HWSZ + p];
#pragma unroll
        for (int i = 0; i < 32; ++i) acc[i] += As[i * 32 + j] * vv;
    }
    unsigned short* ob = obT + (long)b * HWSZ * CC + (long)p * CC + h * HD;
#pragma unroll
    for (int g = 0; g < 4; ++g) {
        u16x8 o;
#pragma unroll
        for (int e = 0; e < 8; ++e) o[e] = f2bf(acc[g * 8 + e]);
        *(u16x8*)&ob[g * 8] = o;
    }
}

// ---------------------------------------------------------------------------
extern "C" void kernel_launch(void* const* d_in, const int* in_sizes, int n_in,
                              void* d_out, int out_size, void* d_ws, size_t ws_size,
                              hipStream_t stream)
{
    const float* x      = (const float*)d_in[0];
    const float* w_qkv  = (const float*)d_in[1];
    const float* w_dw   = (const float*)d_in[2];
    const float* w_proj = (const float*)d_in[3];
    const float* temp   = (const float*)d_in[4];
    float* out = (float*)d_out;
    float* ws  = (float*)d_ws;

    const size_t dwF = (size_t)BB * C3 * HWSZ;                 // 38,535,168
    const size_t atF = (size_t)BB * HEADS * HD * HD;           // 131,072
    const size_t grF = (size_t)NCHUNK * BB * HEADS * SLAB;     // 974,848
    const size_t xbE = (size_t)BB * HWSZ * CC;                 // 12,845,056 ushorts
    const size_t pbF = (size_t)C3 * HWSZ;                      // 2,408,448

    float* dw   = ws;
    float* at   = ws + dwF;
    float* gram = ws + dwF + atF;
    unsigned short* xbT = (unsigned short*)(ws + dwF + atF + grF);
    unsigned short* obT = xbT + xbE;
    unsigned short* wqb = obT + xbE;
    unsigned short* wpb = wqb + (size_t)C3 * CC;
    float* tmp = (float*)(wpb + (size_t)CC * CC);

    const size_t baseF = dwF + atF + grF + (2 * xbE + (size_t)C3 * CC + (size_t)CC * CC + 1) / 2;
    long availF = (long)(ws_size / 4) - (long)baseF;
    long gl = availF / (long)pbF;
    if (gl < 1) gl = 1;
    if (gl > BB) gl = BB;
    const int g = (int)gl;

    cvt_x_T<<<dim3(49, 4, BB), 256, 0, stream>>>(x, xbT);
    cvt_w<<<dim3((C3 * CC) / 2048), 256, 0, stream>>>(w_qkv, wqb);
    cvt_w<<<dim3((CC * CC) / 2048), 256, 0, stream>>>(w_proj, wpb);

    for (int b0 = 0; b0 < BB; b0 += g) {
        int gc = g < (BB - b0) ? g : (BB - b0);
        gemm_mfma<<<dim3(49, 6, gc), 256, 0, stream>>>(
            wqb, xbT + (size_t)b0 * HWSZ * CC, tmp,
            (long)HWSZ * CC, (long)C3 * HWSZ);
        dwconv3x3<<<dim3(13, C3, gc), 256, 0, stream>>>(tmp, w_dw, dw, b0);
    }
    gram_partial<<<dim3(NCHUNK, HEADS, BB), 256, 0, stream>>>(dw, gram);
    attn_finish<<<dim3(HEADS, BB), 1024, 0, stream>>>(gram, temp, at);
    attn_apply<<<dim3(13, HEADS, BB), 256, 0, stream>>>(dw, at, obT);
    gemm_mfma<<<dim3(49, 2, BB), 256, 0, stream>>>(
        wpb, obT, out, (long)HWSZ * CC, (long)CC * HWSZ);
}

// Round 4
// 244.853 us; speedup vs baseline: 3.3858x; 1.6537x over previous
//
#include <hip/hip_runtime.h>
#include <math.h>

#define BB 16
#define CC 256
#define C3 768
#define HH 56
#define WW 56
#define HWSZ 3136
#define HEADS 8
#define HD 32
#define EPSF 1e-12f
#define NCHUNK 7
#define CPX (HWSZ / NCHUNK)   // 448
#define SLAB 1088             // 32*32 gram + 32 q-sumsq + 32 k-sumsq

using s16x8 = __attribute__((ext_vector_type(8))) short;
using u16x8 = __attribute__((ext_vector_type(8))) unsigned short;
using f32x4 = __attribute__((ext_vector_type(4))) float;

__device__ inline unsigned short f2bf(float f) {
    unsigned int u = __float_as_uint(f);
    return (unsigned short)((u + 0x7FFFu + ((u >> 16) & 1u)) >> 16);
}
__device__ inline float bf2f(unsigned short s) {
    return __uint_as_float((unsigned int)s << 16);
}

// ---------------------------------------------------------------------------
// Convert + transpose: x fp32 [256][3136] -> xbT bf16 [3136][256] (per batch).
// ---------------------------------------------------------------------------
__global__ __launch_bounds__(256)
void cvt_x_T(const float* __restrict__ X, unsigned short* __restrict__ XT)
{
    __shared__ float L[64][65];
    const int t = threadIdx.x;
    const int n0 = blockIdx.x * 64;
    const int c0 = blockIdx.y * 64;
    const long bofX = (long)blockIdx.z * CC * HWSZ;
    const long bofT = (long)blockIdx.z * HWSZ * CC;
#pragma unroll
    for (int l = 0; l < 4; ++l) {
        int idx = l * 256 + t;
        int ch = idx >> 4, n4 = (idx & 15) * 4;
        float4 v = *(const float4*)&X[bofX + (long)(c0 + ch) * HWSZ + n0 + n4];
        L[n4 + 0][ch] = v.x; L[n4 + 1][ch] = v.y;
        L[n4 + 2][ch] = v.z; L[n4 + 3][ch] = v.w;
    }
    __syncthreads();
#pragma unroll
    for (int l = 0; l < 2; ++l) {
        int idx = l * 256 + t;
        int r = idx >> 3, c8 = (idx & 7) * 8;
        u16x8 o;
#pragma unroll
        for (int e = 0; e < 8; ++e) o[e] = f2bf(L[r][c8 + e]);
        *(u16x8*)&XT[bofT + (long)(n0 + r) * CC + c0 + c8] = o;
    }
}

// ---------------------------------------------------------------------------
// fp32 -> bf16 flat convert (weights). n multiple of 2048; grid n/2048.
// ---------------------------------------------------------------------------
__global__ __launch_bounds__(256)
void cvt_w(const float* __restrict__ A, unsigned short* __restrict__ B)
{
    int i = (blockIdx.x * 256 + threadIdx.x) * 8;
    float4 a = *(const float4*)&A[i];
    float4 b = *(const float4*)&A[i + 4];
    u16x8 o;
    o[0] = f2bf(a.x); o[1] = f2bf(a.y); o[2] = f2bf(a.z); o[3] = f2bf(a.w);
    o[4] = f2bf(b.x); o[5] = f2bf(b.y); o[6] = f2bf(b.z); o[7] = f2bf(b.w);
    *(u16x8*)&B[i] = o;
}

// ---------------------------------------------------------------------------
// MFMA GEMM: Y[z][m][n] = sum_k W[m][k] * X[z][n][k]   (X is n-major bf16)
// tile 128m x 64n, 4 waves (each 64m x 32n), K=256 in 8 steps of 32.
// grid (49, M/128, z), block 256. bf16out: write bf16 instead of fp32.
// ---------------------------------------------------------------------------
__global__ __launch_bounds__(256)
void gemm_mfma(const unsigned short* __restrict__ Wb,
               const unsigned short* __restrict__ XT,
               void* __restrict__ Yv,
               long xStride, long yStride, int bf16out)
{
    __shared__ __align__(16) unsigned short As[128][40];
    __shared__ __align__(16) unsigned short Bs[64][40];
    const int t = threadIdx.x;
    const int z = blockIdx.z;
    const unsigned short* Xb = XT + (long)z * xStride;
    const int n0 = blockIdx.x * 64;
    const int m0 = blockIdx.y * 128;

    const int w = t >> 6, lane = t & 63;
    const int m_off = (w >> 1) * 64, n_off = (w & 1) * 32;
    const int lr = lane & 15, lk = (lane >> 4) * 8;

    f32x4 acc[4][2];
#pragma unroll
    for (int i = 0; i < 4; ++i)
#pragma unroll
        for (int j = 0; j < 2; ++j) acc[i][j] = (f32x4){0.f, 0.f, 0.f, 0.f};

    const int am = t >> 2, akc = (t & 3) * 8;
    const int bn = t >> 2, bkc = (t & 3) * 8;

    for (int k0 = 0; k0 < 256; k0 += 32) {
        *(u16x8*)&As[am][akc] =
            *(const u16x8*)&Wb[(long)(m0 + am) * 256 + k0 + akc];
        *(u16x8*)&As[64 + am][akc] =
            *(const u16x8*)&Wb[(long)(m0 + 64 + am) * 256 + k0 + akc];
        *(u16x8*)&Bs[bn][bkc] =
            *(const u16x8*)&Xb[(long)(n0 + bn) * 256 + k0 + bkc];
        __syncthreads();
        s16x8 af[4], bf[2];
#pragma unroll
        for (int i = 0; i < 4; ++i)
            af[i] = *(const s16x8*)&As[m_off + i * 16 + lr][lk];
#pragma unroll
        for (int j = 0; j < 2; ++j)
            bf[j] = *(const s16x8*)&Bs[n_off + j * 16 + lr][lk];
#pragma unroll
        for (int i = 0; i < 4; ++i)
#pragma unroll
            for (int j = 0; j < 2; ++j)
                acc[i][j] = __builtin_amdgcn_mfma_f32_16x16x32_bf16(
                    af[i], bf[j], acc[i][j], 0, 0, 0);
        __syncthreads();
    }
    const int orow = (lane >> 4) * 4, ocol = lane & 15;
    if (bf16out) {
        unsigned short* Yb = (unsigned short*)Yv + (long)z * yStride;
#pragma unroll
        for (int i = 0; i < 4; ++i)
#pragma unroll
            for (int j = 0; j < 2; ++j)
#pragma unroll
                for (int r = 0; r < 4; ++r)
                    Yb[(long)(m0 + m_off + i * 16 + orow + r) * HWSZ
                       + n0 + n_off + j * 16 + ocol] = f2bf(acc[i][j][r]);
    } else {
        float* Yb = (float*)Yv + (long)z * yStride;
#pragma unroll
        for (int i = 0; i < 4; ++i)
#pragma unroll
            for (int j = 0; j < 2; ++j)
#pragma unroll
                for (int r = 0; r < 4; ++r)
                    Yb[(long)(m0 + m_off + i * 16 + orow + r) * HWSZ
                       + n0 + n_off + j * 16 + ocol] = acc[i][j][r];
    }
}

// ---------------------------------------------------------------------------
// Depthwise 3x3, pad 1 — LDS-staged plane kernel.
// One block per (ch, z): stage 56x56 bf16 plane into LDS fp32, each thread
// computes float4 outputs (aligned float4 never crosses a row: 56 % 4 == 0).
// grid (768, gc), block 256.
// ---------------------------------------------------------------------------
__global__ __launch_bounds__(256)
void dwconv3x3(const unsigned short* __restrict__ X,
               const float* __restrict__ Wd,
               float* __restrict__ Y,
               int b0)
{
    __shared__ float P[HWSZ];
    const int ch = blockIdx.x;
    const int z = blockIdx.y;
    const int t = threadIdx.x;
    const unsigned short* xc = X + ((long)z * C3 + ch) * HWSZ;
#pragma unroll
    for (int l = 0; l < 2; ++l) {
        int i8 = l * 256 + t;
        if (i8 < HWSZ / 8) {
            u16x8 v = *(const u16x8*)&xc[i8 * 8];
#pragma unroll
            for (int e = 0; e < 8; ++e) P[i8 * 8 + e] = bf2f(v[e]);
        }
    }
    float w9[9];
#pragma unroll
    for (int q = 0; q < 9; ++q) w9[q] = Wd[ch * 9 + q];
    __syncthreads();

    float* yc = Y + ((long)(b0 + z) * C3 + ch) * HWSZ;
#pragma unroll
    for (int l = 0; l < 4; ++l) {
        int q4 = l * 256 + t;
        if (q4 < HWSZ / 4) {
            int p4 = q4 * 4;
            int i = p4 / WW, j0 = p4 % WW;
            float o[4];
#pragma unroll
            for (int e = 0; e < 4; ++e) {
                int j = j0 + e;
                float s = 0.f;
#pragma unroll
                for (int di = 0; di < 3; ++di) {
                    int ii = i + di - 1;
                    if (ii < 0 || ii >= HH) continue;
                    const float* Pr = &P[ii * WW];
#pragma unroll
                    for (int dj = 0; dj < 3; ++dj) {
                        int jj = j + dj - 1;
                        if (jj < 0 || jj >= WW) continue;
                        s += w9[di * 3 + dj] * Pr[jj];
                    }
                }
                o[e] = s;
            }
            *(float4*)&yc[p4] = make_float4(o[0], o[1], o[2], o[3]);
        }
    }
}

// ---------------------------------------------------------------------------
// Phase A: partial Gram (448 px per block). grid (7, 8, 16), block 256.
// ---------------------------------------------------------------------------
__global__ __launch_bounds__(256)
void gram_partial(const float* __restrict__ dw, float* __restrict__ gram)
{
    __shared__ __align__(16) float qT[64][34];
    __shared__ __align__(16) float kT[64][34];
    const int c = blockIdx.x, h = blockIdx.y, b = blockIdx.z;
    const int t = threadIdx.x;
    const float* qb = dw + ((long)b * C3 + h * HD) * HWSZ;
    const float* kb = dw + ((long)b * C3 + CC + h * HD) * HWSZ;
    const int r  = t >> 3;
    const int pl = (t & 7) * 8;
    const int i2 = (t >> 4) * 2;
    const int j2 = (t & 15) * 2;

    float a00 = 0.f, a01 = 0.f, a10 = 0.f, a11 = 0.f;
    float qss = 0.f, kss = 0.f;
    const int base = c * CPX;

    for (int t0 = 0; t0 < CPX; t0 += 64) {
        const float* qp = &qb[(long)r * HWSZ + base + t0 + pl];
        const float* kp = &kb[(long)r * HWSZ + base + t0 + pl];
        float4 qa = *(const float4*)qp;
        float4 qc = *(const float4*)(qp + 4);
        float4 ka = *(const float4*)kp;
        float4 kc = *(const float4*)(kp + 4);
        qss += qa.x*qa.x + qa.y*qa.y + qa.z*qa.z + qa.w*qa.w
             + qc.x*qc.x + qc.y*qc.y + qc.z*qc.z + qc.w*qc.w;
        kss += ka.x*ka.x + ka.y*ka.y + ka.z*ka.z + ka.w*ka.w
             + kc.x*kc.x + kc.y*kc.y + kc.z*kc.z + kc.w*kc.w;
        qT[pl+0][r] = qa.x; qT[pl+1][r] = qa.y; qT[pl+2][r] = qa.z; qT[pl+3][r] = qa.w;
        qT[pl+4][r] = qc.x; qT[pl+5][r] = qc.y; qT[pl+6][r] = qc.z; qT[pl+7][r] = qc.w;
        kT[pl+0][r] = ka.x; kT[pl+1][r] = ka.y; kT[pl+2][r] = ka.z; kT[pl+3][r] = ka.w;
        kT[pl+4][r] = kc.x; kT[pl+5][r] = kc.y; kT[pl+6][r] = kc.z; kT[pl+7][r] = kc.w;
        __syncthreads();
#pragma unroll
        for (int p = 0; p < 64; ++p) {
            float2 q2 = *(const float2*)&qT[p][i2];
            float2 k2 = *(const float2*)&kT[p][j2];
            a00 += q2.x * k2.x; a01 += q2.x * k2.y;
            a10 += q2.y * k2.x; a11 += q2.y * k2.y;
        }
        __syncthreads();
    }

    float* slab = gram + (((long)c * BB + b) * HEADS + h) * SLAB;
    slab[(i2+0) * 32 + j2+0] = a00;
    slab[(i2+0) * 32 + j2+1] = a01;
    slab[(i2+1) * 32 + j2+0] = a10;
    slab[(i2+1) * 32 + j2+1] = a11;
    qss += __shfl_xor(qss, 1); qss += __shfl_xor(qss, 2); qss += __shfl_xor(qss, 4);
    kss += __shfl_xor(kss, 1); kss += __shfl_xor(kss, 2); kss += __shfl_xor(kss, 4);
    if ((t & 7) == 0) { slab[1024 + r] = qss; slab[1056 + r] = kss; }
}

// ---------------------------------------------------------------------------
// Phase B: sum slabs, normalize, temperature, softmax over j. grid (8,16).
// ---------------------------------------------------------------------------
__global__ __launch_bounds__(1024)
void attn_finish(const float* __restrict__ gram,
                 const float* __restrict__ temp,
                 float* __restrict__ attn)
{
    __shared__ float nrm[64];
    const int h = blockIdx.x, b = blockIdx.y;
    const int t = threadIdx.x;
    const long sbase = ((long)b * HEADS + h) * SLAB;
    const long cstr  = (long)BB * HEADS * SLAB;
    if (t < 64) {
        float s = 0.f;
#pragma unroll
        for (int c = 0; c < NCHUNK; ++c) s += gram[c * cstr + sbase + 1024 + t];
        nrm[t] = fmaxf(sqrtf(s), EPSF);
    }
    __syncthreads();
    const int i = t >> 5, j = t & 31;
    float s = 0.f;
#pragma unroll
    for (int c = 0; c < NCHUNK; ++c) s += gram[c * cstr + sbase + i * 32 + j];
    s *= temp[h] / (nrm[i] * nrm[32 + j]);
    float mx = s;
    mx = fmaxf(mx, __shfl_xor(mx, 1));
    mx = fmaxf(mx, __shfl_xor(mx, 2));
    mx = fmaxf(mx, __shfl_xor(mx, 4));
    mx = fmaxf(mx, __shfl_xor(mx, 8));
    mx = fmaxf(mx, __shfl_xor(mx, 16));
    float e = expf(s - mx);
    float sum = e;
    sum += __shfl_xor(sum, 1); sum += __shfl_xor(sum, 2);
    sum += __shfl_xor(sum, 4); sum += __shfl_xor(sum, 8);
    sum += __shfl_xor(sum, 16);
    attn[(((long)b * HEADS + h) * HD + i) * HD + j] = e / sum;
}

// ---------------------------------------------------------------------------
// out[b, p, h*32+i] (bf16, n-major for proj GEMM) = sum_j attn * v[b,h,j,p]
// ---------------------------------------------------------------------------
__global__ __launch_bounds__(256)
void attn_apply(const float* __restrict__ dw,
                const float* __restrict__ attn,
                unsigned short* __restrict__ obT)
{
    __shared__ float As[HD * HD];
    const int h = blockIdx.y, b = blockIdx.z;
    const int t = threadIdx.x;
    const float* ab = attn + ((long)b * HEADS + h) * HD * HD;
#pragma unroll
    for (int l = 0; l < 4; ++l) As[l * 256 + t] = ab[l * 256 + t];
    __syncthreads();
    const int p = blockIdx.x * 256 + t;
    if (p >= HWSZ) return;
    const float* vb = dw + ((long)b * C3 + 2 * CC + h * HD) * HWSZ;
    float acc[32];
#pragma unroll
    for (int i = 0; i < 32; ++i) acc[i] = 0.f;
    for (int j = 0; j < 32; ++j) {
        float vv = vb[(long)j * HWSZ + p];
#pragma unroll
        for (int i = 0; i < 32; ++i) acc[i] += As[i * 32 + j] * vv;
    }
    unsigned short* ob = obT + (long)b * HWSZ * CC + (long)p * CC + h * HD;
#pragma unroll
    for (int g = 0; g < 4; ++g) {
        u16x8 o;
#pragma unroll
        for (int e = 0; e < 8; ++e) o[e] = f2bf(acc[g * 8 + e]);
        *(u16x8*)&ob[g * 8] = o;
    }
}

// ---------------------------------------------------------------------------
extern "C" void kernel_launch(void* const* d_in, const int* in_sizes, int n_in,
                              void* d_out, int out_size, void* d_ws, size_t ws_size,
                              hipStream_t stream)
{
    const float* x      = (const float*)d_in[0];
    const float* w_qkv  = (const float*)d_in[1];
    const float* w_dw   = (const float*)d_in[2];
    const float* w_proj = (const float*)d_in[3];
    const float* temp   = (const float*)d_in[4];
    float* out = (float*)d_out;
    float* ws  = (float*)d_ws;

    const size_t dwF = (size_t)BB * C3 * HWSZ;                 // 38,535,168 f
    const size_t atF = (size_t)BB * HEADS * HD * HD;           // 131,072 f
    const size_t grF = (size_t)NCHUNK * BB * HEADS * SLAB;     // 974,848 f
    const size_t xbE = (size_t)BB * HWSZ * CC;                 // ushorts
    const size_t pbFh = (size_t)C3 * HWSZ / 2;                 // tmp bf16, in floats

    float* dw   = ws;
    float* at   = ws + dwF;
    float* gram = ws + dwF + atF;
    unsigned short* xbT = (unsigned short*)(ws + dwF + atF + grF);
    unsigned short* obT = xbT + xbE;
    unsigned short* wqb = obT + xbE;
    unsigned short* wpb = wqb + (size_t)C3 * CC;
    // tmp (bf16), 16B aligned
    size_t baseF = dwF + atF + grF + (2 * xbE + (size_t)C3 * CC + (size_t)CC * CC + 1) / 2;
    baseF = (baseF + 3) & ~(size_t)3;
    unsigned short* tmp = (unsigned short*)(ws + baseF);

    long availF = (long)(ws_size / 4) - (long)baseF;
    long gl = availF / (long)pbFh;
    if (gl < 1) gl = 1;
    if (gl > BB) gl = BB;
    const int g = (int)gl;

    cvt_x_T<<<dim3(49, 4, BB), 256, 0, stream>>>(x, xbT);
    cvt_w<<<dim3((C3 * CC) / 2048), 256, 0, stream>>>(w_qkv, wqb);
    cvt_w<<<dim3((CC * CC) / 2048), 256, 0, stream>>>(w_proj, wpb);

    for (int b0 = 0; b0 < BB; b0 += g) {
        int gc = g < (BB - b0) ? g : (BB - b0);
        gemm_mfma<<<dim3(49, 6, gc), 256, 0, stream>>>(
            wqb, xbT + (size_t)b0 * HWSZ * CC, tmp,
            (long)HWSZ * CC, (long)C3 * HWSZ, 1);
        dwconv3x3<<<dim3(C3, gc), 256, 0, stream>>>(tmp, w_dw, dw, b0);
    }
    gram_partial<<<dim3(NCHUNK, HEADS, BB), 256, 0, stream>>>(dw, gram);
    attn_finish<<<dim3(HEADS, BB), 1024, 0, stream>>>(gram, temp, at);
    attn_apply<<<dim3(13, HEADS, BB), 256, 0, stream>>>(dw, at, obT);
    gemm_mfma<<<dim3(49, 2, BB), 256, 0, stream>>>(
        wpb, obT, out, (long)HWSZ * CC, (long)CC * HWSZ, 0);
}

// Round 5
// 204.630 us; speedup vs baseline: 4.0514x; 1.1966x over previous
//
#include <hip/hip_runtime.h>
#include <math.h>

#define BB 16
#define CC 256
#define C3 768
#define HH 56
#define WW 56
#define HWSZ 3136
#define HEADS 8
#define HD 32
#define EPSF 1e-12f
#define NCHUNK 7
#define CPX (HWSZ / NCHUNK)   // 448
#define SLAB 1088             // 32*32 gram + 32 q-sumsq + 32 k-sumsq

using s16x8 = __attribute__((ext_vector_type(8))) short;
using u16x8 = __attribute__((ext_vector_type(8))) unsigned short;
using u16x4 = __attribute__((ext_vector_type(4))) unsigned short;
using f32x4 = __attribute__((ext_vector_type(4))) float;

__device__ inline unsigned short f2bf(float f) {
    unsigned int u = __float_as_uint(f);
    return (unsigned short)((u + 0x7FFFu + ((u >> 16) & 1u)) >> 16);
}
__device__ inline float bf2f(unsigned short s) {
    return __uint_as_float((unsigned int)s << 16);
}

// ---------------------------------------------------------------------------
// Convert + transpose: x fp32 [256][3136] -> xbT bf16 [3136][256] (per batch).
// ---------------------------------------------------------------------------
__global__ __launch_bounds__(256)
void cvt_x_T(const float* __restrict__ X, unsigned short* __restrict__ XT)
{
    __shared__ float L[64][65];
    const int t = threadIdx.x;
    const int n0 = blockIdx.x * 64;
    const int c0 = blockIdx.y * 64;
    const long bofX = (long)blockIdx.z * CC * HWSZ;
    const long bofT = (long)blockIdx.z * HWSZ * CC;
#pragma unroll
    for (int l = 0; l < 4; ++l) {
        int idx = l * 256 + t;
        int ch = idx >> 4, n4 = (idx & 15) * 4;
        float4 v = *(const float4*)&X[bofX + (long)(c0 + ch) * HWSZ + n0 + n4];
        L[n4 + 0][ch] = v.x; L[n4 + 1][ch] = v.y;
        L[n4 + 2][ch] = v.z; L[n4 + 3][ch] = v.w;
    }
    __syncthreads();
#pragma unroll
    for (int l = 0; l < 2; ++l) {
        int idx = l * 256 + t;
        int r = idx >> 3, c8 = (idx & 7) * 8;
        u16x8 o;
#pragma unroll
        for (int e = 0; e < 8; ++e) o[e] = f2bf(L[r][c8 + e]);
        *(u16x8*)&XT[bofT + (long)(n0 + r) * CC + c0 + c8] = o;
    }
}

// ---------------------------------------------------------------------------
// fp32 -> bf16 flat convert (weights). n multiple of 2048; grid n/2048.
// ---------------------------------------------------------------------------
__global__ __launch_bounds__(256)
void cvt_w(const float* __restrict__ A, unsigned short* __restrict__ B)
{
    int i = (blockIdx.x * 256 + threadIdx.x) * 8;
    float4 a = *(const float4*)&A[i];
    float4 b = *(const float4*)&A[i + 4];
    u16x8 o;
    o[0] = f2bf(a.x); o[1] = f2bf(a.y); o[2] = f2bf(a.z); o[3] = f2bf(a.w);
    o[4] = f2bf(b.x); o[5] = f2bf(b.y); o[6] = f2bf(b.z); o[7] = f2bf(b.w);
    *(u16x8*)&B[i] = o;
}

// ---------------------------------------------------------------------------
// MFMA GEMM: Y[z][m][n] = sum_k W[m][k] * X[z][n][k]   (X is n-major bf16)
// tile 128m x 64n, 4 waves (each 64m x 32n), K=256 in 8 steps of 32.
// grid (49, M/128, z), block 256. bf16out: write bf16 instead of fp32.
// ---------------------------------------------------------------------------
__global__ __launch_bounds__(256)
void gemm_mfma(const unsigned short* __restrict__ Wb,
               const unsigned short* __restrict__ XT,
               void* __restrict__ Yv,
               long xStride, long yStride, int bf16out)
{
    __shared__ __align__(16) unsigned short As[128][40];
    __shared__ __align__(16) unsigned short Bs[64][40];
    const int t = threadIdx.x;
    const int z = blockIdx.z;
    const unsigned short* Xb = XT + (long)z * xStride;
    const int n0 = blockIdx.x * 64;
    const int m0 = blockIdx.y * 128;

    const int w = t >> 6, lane = t & 63;
    const int m_off = (w >> 1) * 64, n_off = (w & 1) * 32;
    const int lr = lane & 15, lk = (lane >> 4) * 8;

    f32x4 acc[4][2];
#pragma unroll
    for (int i = 0; i < 4; ++i)
#pragma unroll
        for (int j = 0; j < 2; ++j) acc[i][j] = (f32x4){0.f, 0.f, 0.f, 0.f};

    const int am = t >> 2, akc = (t & 3) * 8;
    const int bn = t >> 2, bkc = (t & 3) * 8;

    for (int k0 = 0; k0 < 256; k0 += 32) {
        *(u16x8*)&As[am][akc] =
            *(const u16x8*)&Wb[(long)(m0 + am) * 256 + k0 + akc];
        *(u16x8*)&As[64 + am][akc] =
            *(const u16x8*)&Wb[(long)(m0 + 64 + am) * 256 + k0 + akc];
        *(u16x8*)&Bs[bn][bkc] =
            *(const u16x8*)&Xb[(long)(n0 + bn) * 256 + k0 + bkc];
        __syncthreads();
        s16x8 af[4], bf[2];
#pragma unroll
        for (int i = 0; i < 4; ++i)
            af[i] = *(const s16x8*)&As[m_off + i * 16 + lr][lk];
#pragma unroll
        for (int j = 0; j < 2; ++j)
            bf[j] = *(const s16x8*)&Bs[n_off + j * 16 + lr][lk];
#pragma unroll
        for (int i = 0; i < 4; ++i)
#pragma unroll
            for (int j = 0; j < 2; ++j)
                acc[i][j] = __builtin_amdgcn_mfma_f32_16x16x32_bf16(
                    af[i], bf[j], acc[i][j], 0, 0, 0);
        __syncthreads();
    }
    const int orow = (lane >> 4) * 4, ocol = lane & 15;
    if (bf16out) {
        unsigned short* Yb = (unsigned short*)Yv + (long)z * yStride;
#pragma unroll
        for (int i = 0; i < 4; ++i)
#pragma unroll
            for (int j = 0; j < 2; ++j)
#pragma unroll
                for (int r = 0; r < 4; ++r)
                    Yb[(long)(m0 + m_off + i * 16 + orow + r) * HWSZ
                       + n0 + n_off + j * 16 + ocol] = f2bf(acc[i][j][r]);
    } else {
        float* Yb = (float*)Yv + (long)z * yStride;
#pragma unroll
        for (int i = 0; i < 4; ++i)
#pragma unroll
            for (int j = 0; j < 2; ++j)
#pragma unroll
                for (int r = 0; r < 4; ++r)
                    Yb[(long)(m0 + m_off + i * 16 + orow + r) * HWSZ
                       + n0 + n_off + j * 16 + ocol] = acc[i][j][r];
    }
}

// ---------------------------------------------------------------------------
// Depthwise 3x3, pad 1 — LDS plane kernel, conflict-free.
// Stage: one float4 per thread at lane-sequential 16B (0 conflicts).
// Compute: one pixel per lane, stride-1 (2 lanes/bank = free).
// In bf16, out bf16. grid (768, gc), block 256.
// ---------------------------------------------------------------------------
__global__ __launch_bounds__(256)
void dwconv3x3(const unsigned short* __restrict__ X,
               const float* __restrict__ Wd,
               unsigned short* __restrict__ Y,
               int b0)
{
    __shared__ float P[HWSZ];
    const int ch = blockIdx.x;
    const int z = blockIdx.y;
    const int t = threadIdx.x;
    const unsigned short* xc = X + ((long)z * C3 + ch) * HWSZ;
#pragma unroll
    for (int l = 0; l < 3; ++l) {
        int q4 = l * 256 + t;                 // 0..767
        u16x4 v = *(const u16x4*)&xc[q4 * 4];
        float4 f = make_float4(bf2f(v[0]), bf2f(v[1]), bf2f(v[2]), bf2f(v[3]));
        *(float4*)&P[q4 * 4] = f;
    }
    if (t < 16) {
        int q4 = 768 + t;                     // tail 64 px
        u16x4 v = *(const u16x4*)&xc[q4 * 4];
        *(float4*)&P[q4 * 4] =
            make_float4(bf2f(v[0]), bf2f(v[1]), bf2f(v[2]), bf2f(v[3]));
    }
    float w9[9];
#pragma unroll
    for (int q = 0; q < 9; ++q) w9[q] = Wd[ch * 9 + q];
    __syncthreads();

    unsigned short* yc = Y + ((long)(b0 + z) * C3 + ch) * HWSZ;
    for (int l = 0; l < 13; ++l) {
        int p = l * 256 + t;
        if (p < HWSZ) {
            int i = p / WW, j = p - i * WW;
            float s = 0.f;
#pragma unroll
            for (int di = 0; di < 3; ++di) {
                int ii = i + di - 1;
                if ((unsigned)ii >= HH) continue;
                const float* Pr = &P[ii * WW + j];
                if (j > 0)      s += w9[di * 3 + 0] * Pr[-1];
                                s += w9[di * 3 + 1] * Pr[0];
                if (j < WW - 1) s += w9[di * 3 + 2] * Pr[1];
            }
            yc[p] = f2bf(s);
        }
    }
}

// ---------------------------------------------------------------------------
// Phase A: partial Gram (448 px per block), bf16 input. grid (7,8,16).
// ---------------------------------------------------------------------------
__global__ __launch_bounds__(256)
void gram_partial(const unsigned short* __restrict__ dw, float* __restrict__ gram)
{
    __shared__ __align__(16) float qT[64][34];
    __shared__ __align__(16) float kT[64][34];
    const int c = blockIdx.x, h = blockIdx.y, b = blockIdx.z;
    const int t = threadIdx.x;
    const unsigned short* qb = dw + ((long)b * C3 + h * HD) * HWSZ;
    const unsigned short* kb = dw + ((long)b * C3 + CC + h * HD) * HWSZ;
    const int r  = t >> 3;
    const int pl = (t & 7) * 8;
    const int i2 = (t >> 4) * 2;
    const int j2 = (t & 15) * 2;

    float a00 = 0.f, a01 = 0.f, a10 = 0.f, a11 = 0.f;
    float qss = 0.f, kss = 0.f;
    const int base = c * CPX;

    for (int t0 = 0; t0 < CPX; t0 += 64) {
        u16x8 qv = *(const u16x8*)&qb[(long)r * HWSZ + base + t0 + pl];
        u16x8 kv = *(const u16x8*)&kb[(long)r * HWSZ + base + t0 + pl];
        float qf[8], kf[8];
#pragma unroll
        for (int e = 0; e < 8; ++e) {
            qf[e] = bf2f(qv[e]); kf[e] = bf2f(kv[e]);
            qss += qf[e] * qf[e]; kss += kf[e] * kf[e];
            qT[pl + e][r] = qf[e]; kT[pl + e][r] = kf[e];
        }
        __syncthreads();
#pragma unroll
        for (int p = 0; p < 64; ++p) {
            float2 q2 = *(const float2*)&qT[p][i2];
            float2 k2 = *(const float2*)&kT[p][j2];
            a00 += q2.x * k2.x; a01 += q2.x * k2.y;
            a10 += q2.y * k2.x; a11 += q2.y * k2.y;
        }
        __syncthreads();
    }

    float* slab = gram + (((long)c * BB + b) * HEADS + h) * SLAB;
    slab[(i2+0) * 32 + j2+0] = a00;
    slab[(i2+0) * 32 + j2+1] = a01;
    slab[(i2+1) * 32 + j2+0] = a10;
    slab[(i2+1) * 32 + j2+1] = a11;
    qss += __shfl_xor(qss, 1); qss += __shfl_xor(qss, 2); qss += __shfl_xor(qss, 4);
    kss += __shfl_xor(kss, 1); kss += __shfl_xor(kss, 2); kss += __shfl_xor(kss, 4);
    if ((t & 7) == 0) { slab[1024 + r] = qss; slab[1056 + r] = kss; }
}

// ---------------------------------------------------------------------------
// Phase B: sum slabs, normalize, temperature, softmax over j. grid (8,16).
// ---------------------------------------------------------------------------
__global__ __launch_bounds__(1024)
void attn_finish(const float* __restrict__ gram,
                 const float* __restrict__ temp,
                 float* __restrict__ attn)
{
    __shared__ float nrm[64];
    const int h = blockIdx.x, b = blockIdx.y;
    const int t = threadIdx.x;
    const long sbase = ((long)b * HEADS + h) * SLAB;
    const long cstr  = (long)BB * HEADS * SLAB;
    if (t < 64) {
        float s = 0.f;
#pragma unroll
        for (int c = 0; c < NCHUNK; ++c) s += gram[c * cstr + sbase + 1024 + t];
        nrm[t] = fmaxf(sqrtf(s), EPSF);
    }
    __syncthreads();
    const int i = t >> 5, j = t & 31;
    float s = 0.f;
#pragma unroll
    for (int c = 0; c < NCHUNK; ++c) s += gram[c * cstr + sbase + i * 32 + j];
    s *= temp[h] / (nrm[i] * nrm[32 + j]);
    float mx = s;
    mx = fmaxf(mx, __shfl_xor(mx, 1));
    mx = fmaxf(mx, __shfl_xor(mx, 2));
    mx = fmaxf(mx, __shfl_xor(mx, 4));
    mx = fmaxf(mx, __shfl_xor(mx, 8));
    mx = fmaxf(mx, __shfl_xor(mx, 16));
    float e = expf(s - mx);
    float sum = e;
    sum += __shfl_xor(sum, 1); sum += __shfl_xor(sum, 2);
    sum += __shfl_xor(sum, 4); sum += __shfl_xor(sum, 8);
    sum += __shfl_xor(sum, 16);
    attn[(((long)b * HEADS + h) * HD + i) * HD + j] = e / sum;
}

// ---------------------------------------------------------------------------
// out[b, p, h*32+i] (bf16, n-major for proj GEMM) = sum_j attn * v[b,h,j,p]
// v in bf16. grid (13, 8, 16), block 256.
// ---------------------------------------------------------------------------
__global__ __launch_bounds__(256)
void attn_apply(const unsigned short* __restrict__ dw,
                const float* __restrict__ attn,
                unsigned short* __restrict__ obT)
{
    __shared__ float As[HD * HD];
    const int h = blockIdx.y, b = blockIdx.z;
    const int t = threadIdx.x;
    const float* ab = attn + ((long)b * HEADS + h) * HD * HD;
#pragma unroll
    for (int l = 0; l < 4; ++l) As[l * 256 + t] = ab[l * 256 + t];
    __syncthreads();
    const int p = blockIdx.x * 256 + t;
    if (p >= HWSZ) return;
    const unsigned short* vb = dw + ((long)b * C3 + 2 * CC + h * HD) * HWSZ;
    float acc[32];
#pragma unroll
    for (int i = 0; i < 32; ++i) acc[i] = 0.f;
    for (int j = 0; j < 32; ++j) {
        float vv = bf2f(vb[(long)j * HWSZ + p]);
#pragma unroll
        for (int i = 0; i < 32; ++i) acc[i] += As[i * 32 + j] * vv;
    }
    unsigned short* ob = obT + (long)b * HWSZ * CC + (long)p * CC + h * HD;
#pragma unroll
    for (int g = 0; g < 4; ++g) {
        u16x8 o;
#pragma unroll
        for (int e = 0; e < 8; ++e) o[e] = f2bf(acc[g * 8 + e]);
        *(u16x8*)&ob[g * 8] = o;
    }
}

// ---------------------------------------------------------------------------
extern "C" void kernel_launch(void* const* d_in, const int* in_sizes, int n_in,
                              void* d_out, int out_size, void* d_ws, size_t ws_size,
                              hipStream_t stream)
{
    const float* x      = (const float*)d_in[0];
    const float* w_qkv  = (const float*)d_in[1];
    const float* w_dw   = (const float*)d_in[2];
    const float* w_proj = (const float*)d_in[3];
    const float* temp   = (const float*)d_in[4];
    float* out = (float*)d_out;
    float* ws  = (float*)d_ws;

    const size_t atF = (size_t)BB * HEADS * HD * HD;           // 131,072 f
    const size_t grF = (size_t)NCHUNK * BB * HEADS * SLAB;     // 974,848 f
    const size_t dwE = (size_t)BB * C3 * HWSZ;                 // u16
    const size_t xbE = (size_t)BB * HWSZ * CC;                 // u16
    const size_t pbFh = (size_t)C3 * HWSZ / 2;                 // tmp bf16, floats

    float* at   = ws;
    float* gram = ws + atF;
    unsigned short* dw16 = (unsigned short*)(ws + atF + grF);
    unsigned short* xbT  = dw16 + dwE;
    unsigned short* obT  = xbT + xbE;
    unsigned short* wqb  = obT + xbE;
    unsigned short* wpb  = wqb + (size_t)C3 * CC;
    size_t baseF = atF + grF +
        (dwE + 2 * xbE + (size_t)C3 * CC + (size_t)CC * CC + 1) / 2;
    baseF = (baseF + 3) & ~(size_t)3;
    unsigned short* tmp = (unsigned short*)(ws + baseF);

    long availF = (long)(ws_size / 4) - (long)baseF;
    long gl = availF / (long)pbFh;
    if (gl < 1) gl = 1;
    if (gl > BB) gl = BB;
    const int g = (int)gl;

    cvt_x_T<<<dim3(49, 4, BB), 256, 0, stream>>>(x, xbT);
    cvt_w<<<dim3((C3 * CC) / 2048), 256, 0, stream>>>(w_qkv, wqb);
    cvt_w<<<dim3((CC * CC) / 2048), 256, 0, stream>>>(w_proj, wpb);

    for (int b0 = 0; b0 < BB; b0 += g) {
        int gc = g < (BB - b0) ? g : (BB - b0);
        gemm_mfma<<<dim3(49, 6, gc), 256, 0, stream>>>(
            wqb, xbT + (size_t)b0 * HWSZ * CC, tmp,
            (long)HWSZ * CC, (long)C3 * HWSZ, 1);
        dwconv3x3<<<dim3(C3, gc), 256, 0, stream>>>(tmp, w_dw, dw16, b0);
    }
    gram_partial<<<dim3(NCHUNK, HEADS, BB), 256, 0, stream>>>(dw16, gram);
    attn_finish<<<dim3(HEADS, BB), 1024, 0, stream>>>(gram, temp, at);
    attn_apply<<<dim3(13, HEADS, BB), 256, 0, stream>>>(dw16, at, obT);
    gemm_mfma<<<dim3(49, 2, BB), 256, 0, stream>>>(
        wpb, obT, out, (long)HWSZ * CC, (long)CC * HWSZ, 0);
}

// Round 6
// 197.150 us; speedup vs baseline: 4.2051x; 1.0379x over previous
//
#include <hip/hip_runtime.h>
#include <math.h>

#define BB 16
#define CC 256
#define C3 768
#define HH 56
#define WW 56
#define HWSZ 3136
#define HEADS 8
#define HD 32
#define EPSF 1e-12f
#define NCHUNK 7
#define CPX (HWSZ / NCHUNK)   // 448
#define SLAB 1088             // 32*32 gram + 32 q-sumsq + 32 k-sumsq

using s16x8 = __attribute__((ext_vector_type(8))) short;
using u16x8 = __attribute__((ext_vector_type(8))) unsigned short;
using u16x4 = __attribute__((ext_vector_type(4))) unsigned short;
using f32x4 = __attribute__((ext_vector_type(4))) float;

__device__ inline unsigned short f2bf(float f) {
    unsigned int u = __float_as_uint(f);
    return (unsigned short)((u + 0x7FFFu + ((u >> 16) & 1u)) >> 16);
}
__device__ inline float bf2f(unsigned short s) {
    return __uint_as_float((unsigned int)s << 16);
}
__device__ inline void gload16(const unsigned short* g, const unsigned short* l) {
    __builtin_amdgcn_global_load_lds(
        (const __attribute__((address_space(1))) void*)g,
        (__attribute__((address_space(3))) void*)l, 16, 0, 0);
}

// ---------------------------------------------------------------------------
// Convert + transpose: x fp32 [256][3136] -> xbT bf16 [3136][256] (per batch).
// ---------------------------------------------------------------------------
__global__ __launch_bounds__(256)
void cvt_x_T(const float* __restrict__ X, unsigned short* __restrict__ XT)
{
    __shared__ float L[64][65];
    const int t = threadIdx.x;
    const int n0 = blockIdx.x * 64;
    const int c0 = blockIdx.y * 64;
    const long bofX = (long)blockIdx.z * CC * HWSZ;
    const long bofT = (long)blockIdx.z * HWSZ * CC;
#pragma unroll
    for (int l = 0; l < 4; ++l) {
        int idx = l * 256 + t;
        int ch = idx >> 4, n4 = (idx & 15) * 4;
        float4 v = *(const float4*)&X[bofX + (long)(c0 + ch) * HWSZ + n0 + n4];
        L[n4 + 0][ch] = v.x; L[n4 + 1][ch] = v.y;
        L[n4 + 2][ch] = v.z; L[n4 + 3][ch] = v.w;
    }
    __syncthreads();
#pragma unroll
    for (int l = 0; l < 2; ++l) {
        int idx = l * 256 + t;
        int r = idx >> 3, c8 = (idx & 7) * 8;
        u16x8 o;
#pragma unroll
        for (int e = 0; e < 8; ++e) o[e] = f2bf(L[r][c8 + e]);
        *(u16x8*)&XT[bofT + (long)(n0 + r) * CC + c0 + c8] = o;
    }
}

// ---------------------------------------------------------------------------
// fp32 -> bf16 flat convert (weights). n multiple of 2048; grid n/2048.
// ---------------------------------------------------------------------------
__global__ __launch_bounds__(256)
void cvt_w(const float* __restrict__ A, unsigned short* __restrict__ B)
{
    int i = (blockIdx.x * 256 + threadIdx.x) * 8;
    float4 a = *(const float4*)&A[i];
    float4 b = *(const float4*)&A[i + 4];
    u16x8 o;
    o[0] = f2bf(a.x); o[1] = f2bf(a.y); o[2] = f2bf(a.z); o[3] = f2bf(a.w);
    o[4] = f2bf(b.x); o[5] = f2bf(b.y); o[6] = f2bf(b.z); o[7] = f2bf(b.w);
    *(u16x8*)&B[i] = o;
}

// ---------------------------------------------------------------------------
// MFMA GEMM, m97-style: Y[m][n] = sum_k W[m][k] * X[n][k], K=256.
// 128x128 tile, 4 waves (64x64 each), BK=64, double-buffered LDS staged via
// global_load_lds dwordx4 with XOR-swizzled source (T2: linear LDS dest,
// granule g ^= row&7 involution on both stage-source and ds_read).
// Grid: 1-D nwg = MT * (Nn/128); bijective XCD-chunked swizzle, m-fastest
// (blocks sharing a B-panel land on the same XCD's L2).
// mode 1: Y bf16 row-major [M][Nn].  mode 0: Y fp32 scattered to [b][M][HWSZ].
// ---------------------------------------------------------------------------
__global__ __launch_bounds__(256)
void gemm_mfma2(const unsigned short* __restrict__ Wb,
                const unsigned short* __restrict__ XT,
                void* __restrict__ Yv,
                int MT, long Nn, int mode)
{
    __shared__ __align__(16) unsigned short S[32768];   // 64 KB: 2 x (A 16K + B 16K bytes)
    const int t = threadIdx.x;
    const int w = t >> 6, lane = t & 63;

    const int nwg = (int)gridDim.x;
    const int bid = (int)blockIdx.x;
    const int q8 = nwg >> 3, r8 = nwg & 7;
    const int xcd = bid & 7, idx = bid >> 3;
    const int sw = (xcd < r8 ? xcd * (q8 + 1) : r8 * (q8 + 1) + (xcd - r8) * q8) + idx;
    const int mt = sw % MT, nt = sw / MT;
    const int m0 = mt * 128;
    const long n0 = (long)nt * 128;

    const int rl  = lane >> 3;                 // row-in-8 for staging
    const int gsw = ((lane & 7) ^ rl) << 3;    // swizzled source granule (u16)
    const int lr = lane & 15, gq = lane >> 4;  // frag row / granule
    const int m_off = (w >> 1) * 64, n_off = (w & 1) * 64;

    f32x4 acc[4][4];
#pragma unroll
    for (int i = 0; i < 4; ++i)
#pragma unroll
        for (int j = 0; j < 4; ++j) acc[i][j] = (f32x4){0.f, 0.f, 0.f, 0.f};

    const unsigned short* GA = Wb + (long)m0 * 256;
    const unsigned short* GB = XT + n0 * 256;

#define STAGE(buf, kt)                                                        \
    {                                                                         \
        const unsigned short* L = S + (buf) * 16384;                          \
        const unsigned short* ga = GA + (kt) * 64;                            \
        const unsigned short* gb = GB + (kt) * 64;                            \
        _Pragma("unroll")                                                     \
        for (int qq = 0; qq < 4; ++qq) {                                      \
            int R = w * 32 + qq * 8;                                          \
            gload16(ga + (long)(R + rl) * 256 + gsw, L + R * 64);             \
            gload16(gb + (long)(R + rl) * 256 + gsw, L + 8192 + R * 64);      \
        }                                                                     \
    }

    STAGE(0, 0);
    __syncthreads();
#pragma unroll
    for (int kt = 0; kt < 4; ++kt) {
        if (kt < 3) STAGE((kt + 1) & 1, kt + 1);
        const unsigned short* L = S + (kt & 1) * 16384;
        s16x8 af[4][2], bf[4][2];
#pragma unroll
        for (int i = 0; i < 4; ++i) {
            int r = m_off + i * 16 + lr;
#pragma unroll
            for (int ks = 0; ks < 2; ++ks)
                af[i][ks] = *(const s16x8*)&L[r * 64 + (((gq + ks * 4) ^ (r & 7)) << 3)];
        }
#pragma unroll
        for (int j = 0; j < 4; ++j) {
            int r = n_off + j * 16 + lr;
#pragma unroll
            for (int ks = 0; ks < 2; ++ks)
                bf[j][ks] = *(const s16x8*)&L[8192 + r * 64 + (((gq + ks * 4) ^ (r & 7)) << 3)];
        }
#pragma unroll
        for (int ks = 0; ks < 2; ++ks)
#pragma unroll
            for (int i = 0; i < 4; ++i)
#pragma unroll
                for (int j = 0; j < 4; ++j)
                    acc[i][j] = __builtin_amdgcn_mfma_f32_16x16x32_bf16(
                        af[i][ks], bf[j][ks], acc[i][j], 0, 0, 0);
        __syncthreads();
    }
#undef STAGE

    const int orow = (lane >> 4) * 4, ocol = lane & 15;
    if (mode == 1) {
        unsigned short* Yb = (unsigned short*)Yv;
#pragma unroll
        for (int i = 0; i < 4; ++i)
#pragma unroll
            for (int j = 0; j < 4; ++j) {
                long col = n0 + n_off + j * 16 + ocol;
#pragma unroll
                for (int r = 0; r < 4; ++r)
                    Yb[(long)(m0 + m_off + i * 16 + orow + r) * Nn + col] =
                        f2bf(acc[i][j][r]);
            }
    } else {
        float* Yb = (float*)Yv;
#pragma unroll
        for (int j = 0; j < 4; ++j) {
            long n = n0 + n_off + j * 16 + ocol;
            int z = (int)(n / HWSZ);
            int hw = (int)(n - (long)z * HWSZ);
            float* base = Yb + (long)z * CC * HWSZ + hw;
#pragma unroll
            for (int i = 0; i < 4; ++i)
#pragma unroll
                for (int r = 0; r < 4; ++r)
                    base[(long)(m0 + m_off + i * 16 + orow + r) * HWSZ] = acc[i][j][r];
        }
    }
}

// ---------------------------------------------------------------------------
// Depthwise 3x3, pad 1 — LDS plane kernel, conflict-free.
// tmp layout is now channel-major [768][Nn]; plane (ch, z) at ch*Nn + z*HWSZ.
// grid (768, gc), block 256.
// ---------------------------------------------------------------------------
__global__ __launch_bounds__(256)
void dwconv3x3(const unsigned short* __restrict__ X,
               const float* __restrict__ Wd,
               unsigned short* __restrict__ Y,
               int b0, long Nn)
{
    __shared__ float P[HWSZ];
    const int ch = blockIdx.x;
    const int z = blockIdx.y;
    const int t = threadIdx.x;
    const unsigned short* xc = X + (long)ch * Nn + (long)z * HWSZ;
#pragma unroll
    for (int l = 0; l < 3; ++l) {
        int q4 = l * 256 + t;                 // 0..767
        u16x4 v = *(const u16x4*)&xc[q4 * 4];
        *(float4*)&P[q4 * 4] =
            make_float4(bf2f(v[0]), bf2f(v[1]), bf2f(v[2]), bf2f(v[3]));
    }
    if (t < 16) {
        int q4 = 768 + t;                     // tail 64 px
        u16x4 v = *(const u16x4*)&xc[q4 * 4];
        *(float4*)&P[q4 * 4] =
            make_float4(bf2f(v[0]), bf2f(v[1]), bf2f(v[2]), bf2f(v[3]));
    }
    float w9[9];
#pragma unroll
    for (int q = 0; q < 9; ++q) w9[q] = Wd[ch * 9 + q];
    __syncthreads();

    unsigned short* yc = Y + ((long)(b0 + z) * C3 + ch) * HWSZ;
    for (int l = 0; l < 13; ++l) {
        int p = l * 256 + t;
        if (p < HWSZ) {
            int i = p / WW, j = p - i * WW;
            float s = 0.f;
#pragma unroll
            for (int di = 0; di < 3; ++di) {
                int ii = i + di - 1;
                if ((unsigned)ii >= HH) continue;
                const float* Pr = &P[ii * WW + j];
                if (j > 0)      s += w9[di * 3 + 0] * Pr[-1];
                                s += w9[di * 3 + 1] * Pr[0];
                if (j < WW - 1) s += w9[di * 3 + 2] * Pr[1];
            }
            yc[p] = f2bf(s);
        }
    }
}

// ---------------------------------------------------------------------------
// Phase A: partial Gram (448 px per block), bf16 input. grid (7,8,16).
// ---------------------------------------------------------------------------
__global__ __launch_bounds__(256)
void gram_partial(const unsigned short* __restrict__ dw, float* __restrict__ gram)
{
    __shared__ __align__(16) float qT[64][34];
    __shared__ __align__(16) float kT[64][34];
    const int c = blockIdx.x, h = blockIdx.y, b = blockIdx.z;
    const int t = threadIdx.x;
    const unsigned short* qb = dw + ((long)b * C3 + h * HD) * HWSZ;
    const unsigned short* kb = dw + ((long)b * C3 + CC + h * HD) * HWSZ;
    const int r  = t >> 3;
    const int pl = (t & 7) * 8;
    const int i2 = (t >> 4) * 2;
    const int j2 = (t & 15) * 2;

    float a00 = 0.f, a01 = 0.f, a10 = 0.f, a11 = 0.f;
    float qss = 0.f, kss = 0.f;
    const int base = c * CPX;

    for (int t0 = 0; t0 < CPX; t0 += 64) {
        u16x8 qv = *(const u16x8*)&qb[(long)r * HWSZ + base + t0 + pl];
        u16x8 kv = *(const u16x8*)&kb[(long)r * HWSZ + base + t0 + pl];
        float qf[8], kf[8];
#pragma unroll
        for (int e = 0; e < 8; ++e) {
            qf[e] = bf2f(qv[e]); kf[e] = bf2f(kv[e]);
            qss += qf[e] * qf[e]; kss += kf[e] * kf[e];
            qT[pl + e][r] = qf[e]; kT[pl + e][r] = kf[e];
        }
        __syncthreads();
#pragma unroll
        for (int p = 0; p < 64; ++p) {
            float2 q2 = *(const float2*)&qT[p][i2];
            float2 k2 = *(const float2*)&kT[p][j2];
            a00 += q2.x * k2.x; a01 += q2.x * k2.y;
            a10 += q2.y * k2.x; a11 += q2.y * k2.y;
        }
        __syncthreads();
    }

    float* slab = gram + (((long)c * BB + b) * HEADS + h) * SLAB;
    slab[(i2+0) * 32 + j2+0] = a00;
    slab[(i2+0) * 32 + j2+1] = a01;
    slab[(i2+1) * 32 + j2+0] = a10;
    slab[(i2+1) * 32 + j2+1] = a11;
    qss += __shfl_xor(qss, 1); qss += __shfl_xor(qss, 2); qss += __shfl_xor(qss, 4);
    kss += __shfl_xor(kss, 1); kss += __shfl_xor(kss, 2); kss += __shfl_xor(kss, 4);
    if ((t & 7) == 0) { slab[1024 + r] = qss; slab[1056 + r] = kss; }
}

// ---------------------------------------------------------------------------
// Phase B: sum slabs, normalize, temperature, softmax over j. grid (8,16).
// ---------------------------------------------------------------------------
__global__ __launch_bounds__(1024)
void attn_finish(const float* __restrict__ gram,
                 const float* __restrict__ temp,
                 float* __restrict__ attn)
{
    __shared__ float nrm[64];
    const int h = blockIdx.x, b = blockIdx.y;
    const int t = threadIdx.x;
    const long sbase = ((long)b * HEADS + h) * SLAB;
    const long cstr  = (long)BB * HEADS * SLAB;
    if (t < 64) {
        float s = 0.f;
#pragma unroll
        for (int c = 0; c < NCHUNK; ++c) s += gram[c * cstr + sbase + 1024 + t];
        nrm[t] = fmaxf(sqrtf(s), EPSF);
    }
    __syncthreads();
    const int i = t >> 5, j = t & 31;
    float s = 0.f;
#pragma unroll
    for (int c = 0; c < NCHUNK; ++c) s += gram[c * cstr + sbase + i * 32 + j];
    s *= temp[h] / (nrm[i] * nrm[32 + j]);
    float mx = s;
    mx = fmaxf(mx, __shfl_xor(mx, 1));
    mx = fmaxf(mx, __shfl_xor(mx, 2));
    mx = fmaxf(mx, __shfl_xor(mx, 4));
    mx = fmaxf(mx, __shfl_xor(mx, 8));
    mx = fmaxf(mx, __shfl_xor(mx, 16));
    float e = expf(s - mx);
    float sum = e;
    sum += __shfl_xor(sum, 1); sum += __shfl_xor(sum, 2);
    sum += __shfl_xor(sum, 4); sum += __shfl_xor(sum, 8);
    sum += __shfl_xor(sum, 16);
    attn[(((long)b * HEADS + h) * HD + i) * HD + j] = e / sum;
}

// ---------------------------------------------------------------------------
// out[b, p, h*32+i] (bf16, n-major for proj GEMM) = sum_j attn * v[b,h,j,p]
// v in bf16. grid (13, 8, 16), block 256.
// ---------------------------------------------------------------------------
__global__ __launch_bounds__(256)
void attn_apply(const unsigned short* __restrict__ dw,
                const float* __restrict__ attn,
                unsigned short* __restrict__ obT)
{
    __shared__ float As[HD * HD];
    const int h = blockIdx.y, b = blockIdx.z;
    const int t = threadIdx.x;
    const float* ab = attn + ((long)b * HEADS + h) * HD * HD;
#pragma unroll
    for (int l = 0; l < 4; ++l) As[l * 256 + t] = ab[l * 256 + t];
    __syncthreads();
    const int p = blockIdx.x * 256 + t;
    if (p >= HWSZ) return;
    const unsigned short* vb = dw + ((long)b * C3 + 2 * CC + h * HD) * HWSZ;
    float acc[32];
#pragma unroll
    for (int i = 0; i < 32; ++i) acc[i] = 0.f;
    for (int j = 0; j < 32; ++j) {
        float vv = bf2f(vb[(long)j * HWSZ + p]);
#pragma unroll
        for (int i = 0; i < 32; ++i) acc[i] += As[i * 32 + j] * vv;
    }
    unsigned short* ob = obT + (long)b * HWSZ * CC + (long)p * CC + h * HD;
#pragma unroll
    for (int g = 0; g < 4; ++g) {
        u16x8 o;
#pragma unroll
        for (int e = 0; e < 8; ++e) o[e] = f2bf(acc[g * 8 + e]);
        *(u16x8*)&ob[g * 8] = o;
    }
}

// ---------------------------------------------------------------------------
extern "C" void kernel_launch(void* const* d_in, const int* in_sizes, int n_in,
                              void* d_out, int out_size, void* d_ws, size_t ws_size,
                              hipStream_t stream)
{
    const float* x      = (const float*)d_in[0];
    const float* w_qkv  = (const float*)d_in[1];
    const float* w_dw   = (const float*)d_in[2];
    const float* w_proj = (const float*)d_in[3];
    const float* temp   = (const float*)d_in[4];
    float* out = (float*)d_out;
    float* ws  = (float*)d_ws;

    const size_t atF = (size_t)BB * HEADS * HD * HD;           // 131,072 f
    const size_t grF = (size_t)NCHUNK * BB * HEADS * SLAB;     // 974,848 f
    const size_t dwE = (size_t)BB * C3 * HWSZ;                 // u16
    const size_t xbE = (size_t)BB * HWSZ * CC;                 // u16
    const size_t pbFh = (size_t)C3 * HWSZ / 2;                 // tmp bf16 per batch, floats

    float* at   = ws;
    float* gram = ws + atF;
    unsigned short* dw16 = (unsigned short*)(ws + atF + grF);
    unsigned short* xbT  = dw16 + dwE;
    unsigned short* obT  = xbT + xbE;
    unsigned short* wqb  = obT + xbE;
    unsigned short* wpb  = wqb + (size_t)C3 * CC;
    size_t baseF = atF + grF +
        (dwE + 2 * xbE + (size_t)C3 * CC + (size_t)CC * CC + 1) / 2;
    baseF = (baseF + 3) & ~(size_t)3;
    unsigned short* tmp = (unsigned short*)(ws + baseF);

    long availF = (long)(ws_size / 4) - (long)baseF;
    long gl = availF / (long)pbFh;
    if (gl > BB) gl = BB;
    gl &= ~1L;                       // even group (so g*HWSZ % 128 == 0)
    if (gl < 2) gl = 2;
    const int g = (int)gl;

    cvt_x_T<<<dim3(49, 4, BB), 256, 0, stream>>>(x, xbT);
    cvt_w<<<dim3((C3 * CC) / 2048), 256, 0, stream>>>(w_qkv, wqb);
    cvt_w<<<dim3((CC * CC) / 2048), 256, 0, stream>>>(w_proj, wpb);

    for (int b0 = 0; b0 < BB; b0 += g) {
        int gc = g < (BB - b0) ? g : (BB - b0);
        long Ng = (long)gc * HWSZ;
        int nwg = 6 * (int)(Ng / 128);
        gemm_mfma2<<<dim3(nwg), 256, 0, stream>>>(
            wqb, xbT + (size_t)b0 * HWSZ * CC, tmp, 6, Ng, 1);
        dwconv3x3<<<dim3(C3, gc), 256, 0, stream>>>(tmp, w_dw, dw16, b0, Ng);
    }
    gram_partial<<<dim3(NCHUNK, HEADS, BB), 256, 0, stream>>>(dw16, gram);
    attn_finish<<<dim3(HEADS, BB), 1024, 0, stream>>>(gram, temp, at);
    attn_apply<<<dim3(13, HEADS, BB), 256, 0, stream>>>(dw16, at, obT);
    {
        long Nn = (long)BB * HWSZ;               // 50176
        int nwg = 2 * (int)(Nn / 128);           // 784
        gemm_mfma2<<<dim3(nwg), 256, 0, stream>>>(
            wpb, obT, out, 2, Nn, 0);
    }
}

// Round 7
// 185.993 us; speedup vs baseline: 4.4573x; 1.0600x over previous
//
#include <hip/hip_runtime.h>
#include <math.h>

#define BB 16
#define CC 256
#define C3 768
#define HH 56
#define WW 56
#define HWSZ 3136
#define HEADS 8
#define HD 32
#define EPSF 1e-12f
#define NCHUNK 7
#define CPX (HWSZ / NCHUNK)   // 448
#define SLAB 1088             // 32*32 gram + 32 q-sumsq + 32 k-sumsq

using s16x8 = __attribute__((ext_vector_type(8))) short;
using u16x8 = __attribute__((ext_vector_type(8))) unsigned short;
using u16x4 = __attribute__((ext_vector_type(4))) unsigned short;
using f32x4 = __attribute__((ext_vector_type(4))) float;

__device__ inline unsigned short f2bf(float f) {
    unsigned int u = __float_as_uint(f);
    return (unsigned short)((u + 0x7FFFu + ((u >> 16) & 1u)) >> 16);
}
__device__ inline float bf2f(unsigned short s) {
    return __uint_as_float((unsigned int)s << 16);
}
__device__ inline void gload16(const unsigned short* g, const unsigned short* l) {
    __builtin_amdgcn_global_load_lds(
        (const __attribute__((address_space(1))) void*)g,
        (__attribute__((address_space(3))) void*)l, 16, 0, 0);
}

// ---------------------------------------------------------------------------
// Convert + transpose: x fp32 [256][3136] -> xbT bf16 [3136][256] (per batch).
// ---------------------------------------------------------------------------
__global__ __launch_bounds__(256)
void cvt_x_T(const float* __restrict__ X, unsigned short* __restrict__ XT)
{
    __shared__ float L[64][65];
    const int t = threadIdx.x;
    const int n0 = blockIdx.x * 64;
    const int c0 = blockIdx.y * 64;
    const long bofX = (long)blockIdx.z * CC * HWSZ;
    const long bofT = (long)blockIdx.z * HWSZ * CC;
#pragma unroll
    for (int l = 0; l < 4; ++l) {
        int idx = l * 256 + t;
        int ch = idx >> 4, n4 = (idx & 15) * 4;
        float4 v = *(const float4*)&X[bofX + (long)(c0 + ch) * HWSZ + n0 + n4];
        L[n4 + 0][ch] = v.x; L[n4 + 1][ch] = v.y;
        L[n4 + 2][ch] = v.z; L[n4 + 3][ch] = v.w;
    }
    __syncthreads();
#pragma unroll
    for (int l = 0; l < 2; ++l) {
        int idx = l * 256 + t;
        int r = idx >> 3, c8 = (idx & 7) * 8;
        u16x8 o;
#pragma unroll
        for (int e = 0; e < 8; ++e) o[e] = f2bf(L[r][c8 + e]);
        *(u16x8*)&XT[bofT + (long)(n0 + r) * CC + c0 + c8] = o;
    }
}

// ---------------------------------------------------------------------------
// fp32 -> bf16 flat convert (weights). n multiple of 2048; grid n/2048.
// ---------------------------------------------------------------------------
__global__ __launch_bounds__(256)
void cvt_w(const float* __restrict__ A, unsigned short* __restrict__ B)
{
    int i = (blockIdx.x * 256 + threadIdx.x) * 8;
    float4 a = *(const float4*)&A[i];
    float4 b = *(const float4*)&A[i + 4];
    u16x8 o;
    o[0] = f2bf(a.x); o[1] = f2bf(a.y); o[2] = f2bf(a.z); o[3] = f2bf(a.w);
    o[4] = f2bf(b.x); o[5] = f2bf(b.y); o[6] = f2bf(b.z); o[7] = f2bf(b.w);
    *(u16x8*)&B[i] = o;
}

// ---------------------------------------------------------------------------
// MFMA GEMM, m97-style: Y[m][n] = sum_k W[m][k] * X[n][k], K=256.
// 128x128 tile, 4 waves (64x64 each), BK=64, double-buffered LDS via
// global_load_lds dwordx4 with XOR-swizzled source granules.
// ---------------------------------------------------------------------------
__global__ __launch_bounds__(256)
void gemm_mfma2(const unsigned short* __restrict__ Wb,
                const unsigned short* __restrict__ XT,
                void* __restrict__ Yv,
                int MT, long Nn, int mode)
{
    __shared__ __align__(16) unsigned short S[32768];
    const int t = threadIdx.x;
    const int w = t >> 6, lane = t & 63;

    const int nwg = (int)gridDim.x;
    const int bid = (int)blockIdx.x;
    const int q8 = nwg >> 3, r8 = nwg & 7;
    const int xcd = bid & 7, idx = bid >> 3;
    const int sw = (xcd < r8 ? xcd * (q8 + 1) : r8 * (q8 + 1) + (xcd - r8) * q8) + idx;
    const int mt = sw % MT, nt = sw / MT;
    const int m0 = mt * 128;
    const long n0 = (long)nt * 128;

    const int rl  = lane >> 3;
    const int gsw = ((lane & 7) ^ rl) << 3;
    const int lr = lane & 15, gq = lane >> 4;
    const int m_off = (w >> 1) * 64, n_off = (w & 1) * 64;

    f32x4 acc[4][4];
#pragma unroll
    for (int i = 0; i < 4; ++i)
#pragma unroll
        for (int j = 0; j < 4; ++j) acc[i][j] = (f32x4){0.f, 0.f, 0.f, 0.f};

    const unsigned short* GA = Wb + (long)m0 * 256;
    const unsigned short* GB = XT + n0 * 256;

#define STAGE(buf, kt)                                                        \
    {                                                                         \
        const unsigned short* L = S + (buf) * 16384;                          \
        const unsigned short* ga = GA + (kt) * 64;                            \
        const unsigned short* gb = GB + (kt) * 64;                            \
        _Pragma("unroll")                                                     \
        for (int qq = 0; qq < 4; ++qq) {                                      \
            int R = w * 32 + qq * 8;                                          \
            gload16(ga + (long)(R + rl) * 256 + gsw, L + R * 64);             \
            gload16(gb + (long)(R + rl) * 256 + gsw, L + 8192 + R * 64);      \
        }                                                                     \
    }

    STAGE(0, 0);
    __syncthreads();
#pragma unroll
    for (int kt = 0; kt < 4; ++kt) {
        if (kt < 3) STAGE((kt + 1) & 1, kt + 1);
        const unsigned short* L = S + (kt & 1) * 16384;
        s16x8 af[4][2], bf[4][2];
#pragma unroll
        for (int i = 0; i < 4; ++i) {
            int r = m_off + i * 16 + lr;
#pragma unroll
            for (int ks = 0; ks < 2; ++ks)
                af[i][ks] = *(const s16x8*)&L[r * 64 + (((gq + ks * 4) ^ (r & 7)) << 3)];
        }
#pragma unroll
        for (int j = 0; j < 4; ++j) {
            int r = n_off + j * 16 + lr;
#pragma unroll
            for (int ks = 0; ks < 2; ++ks)
                bf[j][ks] = *(const s16x8*)&L[8192 + r * 64 + (((gq + ks * 4) ^ (r & 7)) << 3)];
        }
#pragma unroll
        for (int ks = 0; ks < 2; ++ks)
#pragma unroll
            for (int i = 0; i < 4; ++i)
#pragma unroll
                for (int j = 0; j < 4; ++j)
                    acc[i][j] = __builtin_amdgcn_mfma_f32_16x16x32_bf16(
                        af[i][ks], bf[j][ks], acc[i][j], 0, 0, 0);
        __syncthreads();
    }
#undef STAGE

    const int orow = (lane >> 4) * 4, ocol = lane & 15;
    if (mode == 1) {
        unsigned short* Yb = (unsigned short*)Yv;
#pragma unroll
        for (int i = 0; i < 4; ++i)
#pragma unroll
            for (int j = 0; j < 4; ++j) {
                long col = n0 + n_off + j * 16 + ocol;
#pragma unroll
                for (int r = 0; r < 4; ++r)
                    Yb[(long)(m0 + m_off + i * 16 + orow + r) * Nn + col] =
                        f2bf(acc[i][j][r]);
            }
    } else {
        float* Yb = (float*)Yv;
#pragma unroll
        for (int j = 0; j < 4; ++j) {
            long n = n0 + n_off + j * 16 + ocol;
            int z = (int)(n / HWSZ);
            int hw = (int)(n - (long)z * HWSZ);
            float* base = Yb + (long)z * CC * HWSZ + hw;
#pragma unroll
            for (int i = 0; i < 4; ++i)
#pragma unroll
                for (int r = 0; r < 4; ++r)
                    base[(long)(m0 + m_off + i * 16 + orow + r) * HWSZ] = acc[i][j][r];
        }
    }
}

// ---------------------------------------------------------------------------
// Depthwise 3x3, pad 1 — LDS plane kernel, 4 px/thread via float4 row reads.
// Boundary values from neighbor lanes via shfl (row-wrap lanes coincide with
// zero-pad, so cross-row shuffle garbage is always overridden); wave-edge
// lanes 0/63 read the single boundary float from LDS.
// grid (768, gc), block 256.
// ---------------------------------------------------------------------------
__global__ __launch_bounds__(256)
void dwconv3x3(const unsigned short* __restrict__ X,
               const float* __restrict__ Wd,
               unsigned short* __restrict__ Y,
               int b0, long Nn)
{
    __shared__ float P[HWSZ];
    const int ch = blockIdx.x;
    const int z = blockIdx.y;
    const int t = threadIdx.x;
    const unsigned short* xc = X + (long)ch * Nn + (long)z * HWSZ;
#pragma unroll
    for (int l = 0; l < 3; ++l) {
        int q4 = l * 256 + t;
        u16x4 v = *(const u16x4*)&xc[q4 * 4];
        *(float4*)&P[q4 * 4] =
            make_float4(bf2f(v[0]), bf2f(v[1]), bf2f(v[2]), bf2f(v[3]));
    }
    if (t < 16) {
        int q4 = 768 + t;
        u16x4 v = *(const u16x4*)&xc[q4 * 4];
        *(float4*)&P[q4 * 4] =
            make_float4(bf2f(v[0]), bf2f(v[1]), bf2f(v[2]), bf2f(v[3]));
    }
    float w9[9];
#pragma unroll
    for (int q = 0; q < 9; ++q) w9[q] = Wd[ch * 9 + q];
    __syncthreads();

    unsigned short* yc = Y + ((long)(b0 + z) * C3 + ch) * HWSZ;
    const int lane = t & 63;
#pragma unroll
    for (int l = 0; l < 4; ++l) {
        int g4 = l * 256 + t;               // quad index: 4 px each, 784 total
        if (g4 < 784) {
            int qi = g4 / 14, qj = g4 - qi * 14;
            float o0 = 0.f, o1 = 0.f, o2 = 0.f, o3 = 0.f;
#pragma unroll
            for (int di = 0; di < 3; ++di) {
                int ii = qi + di - 1;
                if ((unsigned)ii >= HH) continue;
                const float* Pr = &P[ii * WW + qj * 4];
                float4 v = *(const float4*)Pr;
                float lf = __shfl_up(v.w, 1);
                float rt = __shfl_down(v.x, 1);
                if (lane == 0 && qj != 0)   lf = Pr[-1];
                if (lane == 63 && qj != 13) rt = Pr[4];
                if (qj == 0)  lf = 0.f;
                if (qj == 13) rt = 0.f;
                const float wL = w9[di * 3 + 0], wC = w9[di * 3 + 1], wR = w9[di * 3 + 2];
                o0 += wL * lf  + wC * v.x + wR * v.y;
                o1 += wL * v.x + wC * v.y + wR * v.z;
                o2 += wL * v.y + wC * v.z + wR * v.w;
                o3 += wL * v.z + wC * v.w + wR * rt;
            }
            u16x4 ov;
            ov[0] = f2bf(o0); ov[1] = f2bf(o1); ov[2] = f2bf(o2); ov[3] = f2bf(o3);
            *(u16x4*)&yc[g4 * 4] = ov;
        }
    }
}

// ---------------------------------------------------------------------------
// Phase A: partial Gram (448 px per block), bf16 input. grid (7,8,16).
// ---------------------------------------------------------------------------
__global__ __launch_bounds__(256)
void gram_partial(const unsigned short* __restrict__ dw, float* __restrict__ gram)
{
    __shared__ __align__(16) float qT[64][34];
    __shared__ __align__(16) float kT[64][34];
    const int c = blockIdx.x, h = blockIdx.y, b = blockIdx.z;
    const int t = threadIdx.x;
    const unsigned short* qb = dw + ((long)b * C3 + h * HD) * HWSZ;
    const unsigned short* kb = dw + ((long)b * C3 + CC + h * HD) * HWSZ;
    const int r  = t >> 3;
    const int pl = (t & 7) * 8;
    const int i2 = (t >> 4) * 2;
    const int j2 = (t & 15) * 2;

    float a00 = 0.f, a01 = 0.f, a10 = 0.f, a11 = 0.f;
    float qss = 0.f, kss = 0.f;
    const int base = c * CPX;

    for (int t0 = 0; t0 < CPX; t0 += 64) {
        u16x8 qv = *(const u16x8*)&qb[(long)r * HWSZ + base + t0 + pl];
        u16x8 kv = *(const u16x8*)&kb[(long)r * HWSZ + base + t0 + pl];
        float qf[8], kf[8];
#pragma unroll
        for (int e = 0; e < 8; ++e) {
            qf[e] = bf2f(qv[e]); kf[e] = bf2f(kv[e]);
            qss += qf[e] * qf[e]; kss += kf[e] * kf[e];
            qT[pl + e][r] = qf[e]; kT[pl + e][r] = kf[e];
        }
        __syncthreads();
#pragma unroll
        for (int p = 0; p < 64; ++p) {
            float2 q2 = *(const float2*)&qT[p][i2];
            float2 k2 = *(const float2*)&kT[p][j2];
            a00 += q2.x * k2.x; a01 += q2.x * k2.y;
            a10 += q2.y * k2.x; a11 += q2.y * k2.y;
        }
        __syncthreads();
    }

    float* slab = gram + (((long)c * BB + b) * HEADS + h) * SLAB;
    slab[(i2+0) * 32 + j2+0] = a00;
    slab[(i2+0) * 32 + j2+1] = a01;
    slab[(i2+1) * 32 + j2+0] = a10;
    slab[(i2+1) * 32 + j2+1] = a11;
    qss += __shfl_xor(qss, 1); qss += __shfl_xor(qss, 2); qss += __shfl_xor(qss, 4);
    kss += __shfl_xor(kss, 1); kss += __shfl_xor(kss, 2); kss += __shfl_xor(kss, 4);
    if ((t & 7) == 0) { slab[1024 + r] = qss; slab[1056 + r] = kss; }
}

// ---------------------------------------------------------------------------
// Phase B: sum slabs, normalize, temperature, softmax over j. grid (8,16).
// ---------------------------------------------------------------------------
__global__ __launch_bounds__(1024)
void attn_finish(const float* __restrict__ gram,
                 const float* __restrict__ temp,
                 float* __restrict__ attn)
{
    __shared__ float nrm[64];
    const int h = blockIdx.x, b = blockIdx.y;
    const int t = threadIdx.x;
    const long sbase = ((long)b * HEADS + h) * SLAB;
    const long cstr  = (long)BB * HEADS * SLAB;
    if (t < 64) {
        float s = 0.f;
#pragma unroll
        for (int c = 0; c < NCHUNK; ++c) s += gram[c * cstr + sbase + 1024 + t];
        nrm[t] = fmaxf(sqrtf(s), EPSF);
    }
    __syncthreads();
    const int i = t >> 5, j = t & 31;
    float s = 0.f;
#pragma unroll
    for (int c = 0; c < NCHUNK; ++c) s += gram[c * cstr + sbase + i * 32 + j];
    s *= temp[h] / (nrm[i] * nrm[32 + j]);
    float mx = s;
    mx = fmaxf(mx, __shfl_xor(mx, 1));
    mx = fmaxf(mx, __shfl_xor(mx, 2));
    mx = fmaxf(mx, __shfl_xor(mx, 4));
    mx = fmaxf(mx, __shfl_xor(mx, 8));
    mx = fmaxf(mx, __shfl_xor(mx, 16));
    float e = expf(s - mx);
    float sum = e;
    sum += __shfl_xor(sum, 1); sum += __shfl_xor(sum, 2);
    sum += __shfl_xor(sum, 4); sum += __shfl_xor(sum, 8);
    sum += __shfl_xor(sum, 16);
    attn[(((long)b * HEADS + h) * HD + i) * HD + j] = e / sum;
}

// ---------------------------------------------------------------------------
// out[b, p, h*32+i] (bf16, n-major for proj GEMM) = sum_j attn * v[b,h,j,p]
// v in bf16. grid (13, 8, 16), block 256.
// ---------------------------------------------------------------------------
__global__ __launch_bounds__(256)
void attn_apply(const unsigned short* __restrict__ dw,
                const float* __restrict__ attn,
                unsigned short* __restrict__ obT)
{
    __shared__ float As[HD * HD];
    const int h = blockIdx.y, b = blockIdx.z;
    const int t = threadIdx.x;
    const float* ab = attn + ((long)b * HEADS + h) * HD * HD;
#pragma unroll
    for (int l = 0; l < 4; ++l) As[l * 256 + t] = ab[l * 256 + t];
    __syncthreads();
    const int p = blockIdx.x * 256 + t;
    if (p >= HWSZ) return;
    const unsigned short* vb = dw + ((long)b * C3 + 2 * CC + h * HD) * HWSZ;
    float acc[32];
#pragma unroll
    for (int i = 0; i < 32; ++i) acc[i] = 0.f;
    for (int j = 0; j < 32; ++j) {
        float vv = bf2f(vb[(long)j * HWSZ + p]);
#pragma unroll
        for (int i = 0; i < 32; ++i) acc[i] += As[i * 32 + j] * vv;
    }
    unsigned short* ob = obT + (long)b * HWSZ * CC + (long)p * CC + h * HD;
#pragma unroll
    for (int g = 0; g < 4; ++g) {
        u16x8 o;
#pragma unroll
        for (int e = 0; e < 8; ++e) o[e] = f2bf(acc[g * 8 + e]);
        *(u16x8*)&ob[g * 8] = o;
    }
}

// ---------------------------------------------------------------------------
extern "C" void kernel_launch(void* const* d_in, const int* in_sizes, int n_in,
                              void* d_out, int out_size, void* d_ws, size_t ws_size,
                              hipStream_t stream)
{
    const float* x      = (const float*)d_in[0];
    const float* w_qkv  = (const float*)d_in[1];
    const float* w_dw   = (const float*)d_in[2];
    const float* w_proj = (const float*)d_in[3];
    const float* temp   = (const float*)d_in[4];
    float* out = (float*)d_out;
    float* ws  = (float*)d_ws;

    const size_t atF = (size_t)BB * HEADS * HD * HD;           // 131,072 f
    const size_t grF = (size_t)NCHUNK * BB * HEADS * SLAB;     // 974,848 f
    const size_t dwE = (size_t)BB * C3 * HWSZ;                 // u16
    const size_t xbE = (size_t)BB * HWSZ * CC;                 // u16
    const size_t pbFh = (size_t)C3 * HWSZ / 2;                 // tmp bf16 per batch, floats

    float* at   = ws;
    float* gram = ws + atF;
    unsigned short* dw16 = (unsigned short*)(ws + atF + grF);
    unsigned short* xbT  = dw16 + dwE;
    unsigned short* obT  = xbT + xbE;
    unsigned short* wqb  = obT + xbE;
    unsigned short* wpb  = wqb + (size_t)C3 * CC;
    size_t baseF = atF + grF +
        (dwE + 2 * xbE + (size_t)C3 * CC + (size_t)CC * CC + 1) / 2;
    baseF = (baseF + 3) & ~(size_t)3;
    unsigned short* tmp = (unsigned short*)(ws + baseF);

    long availF = (long)(ws_size / 4) - (long)baseF;
    long gl = availF / (long)pbFh;
    if (gl > BB) gl = BB;
    gl &= ~1L;
    if (gl < 2) gl = 2;
    const int g = (int)gl;

    cvt_x_T<<<dim3(49, 4, BB), 256, 0, stream>>>(x, xbT);
    cvt_w<<<dim3((C3 * CC) / 2048), 256, 0, stream>>>(w_qkv, wqb);
    cvt_w<<<dim3((CC * CC) / 2048), 256, 0, stream>>>(w_proj, wpb);

    for (int b0 = 0; b0 < BB; b0 += g) {
        int gc = g < (BB - b0) ? g : (BB - b0);
        long Ng = (long)gc * HWSZ;
        int nwg = 6 * (int)(Ng / 128);
        gemm_mfma2<<<dim3(nwg), 256, 0, stream>>>(
            wqb, xbT + (size_t)b0 * HWSZ * CC, tmp, 6, Ng, 1);
        dwconv3x3<<<dim3(C3, gc), 256, 0, stream>>>(tmp, w_dw, dw16, b0, Ng);
    }
    gram_partial<<<dim3(NCHUNK, HEADS, BB), 256, 0, stream>>>(dw16, gram);
    attn_finish<<<dim3(HEADS, BB), 1024, 0, stream>>>(gram, temp, at);
    attn_apply<<<dim3(13, HEADS, BB), 256, 0, stream>>>(dw16, at, obT);
    {
        long Nn = (long)BB * HWSZ;               // 50176
        int nwg = 2 * (int)(Nn / 128);           // 784
        gemm_mfma2<<<dim3(nwg), 256, 0, stream>>>(
            wpb, obT, out, 2, Nn, 0);
    }
}

// Round 8
// 173.743 us; speedup vs baseline: 4.7716x; 1.0705x over previous
//
#include <hip/hip_runtime.h>
#include <math.h>

#define BB 16
#define CC 256
#define C3 768
#define HH 56
#define WW 56
#define HWSZ 3136
#define HEADS 8
#define HD 32
#define EPSF 1e-12f
#define NCHUNK 7
#define SLAB 1088             // 32*32 gram + 32 q-sumsq + 32 k-sumsq

using s16x8 = __attribute__((ext_vector_type(8))) short;
using u16x8 = __attribute__((ext_vector_type(8))) unsigned short;
using u16x4 = __attribute__((ext_vector_type(4))) unsigned short;
using f32x4 = __attribute__((ext_vector_type(4))) float;
using f32x16 = __attribute__((ext_vector_type(16))) float;

__device__ inline unsigned short f2bf(float f) {
    unsigned int u = __float_as_uint(f);
    return (unsigned short)((u + 0x7FFFu + ((u >> 16) & 1u)) >> 16);
}
__device__ inline float bf2f(unsigned short s) {
    return __uint_as_float((unsigned int)s << 16);
}
__device__ inline void gload16(const unsigned short* g, const unsigned short* l) {
    __builtin_amdgcn_global_load_lds(
        (const __attribute__((address_space(1))) void*)g,
        (__attribute__((address_space(3))) void*)l, 16, 0, 0);
}

// ---------------------------------------------------------------------------
// Convert + transpose: x fp32 [256][3136] -> xbT bf16 [3136][256] (per batch).
// ---------------------------------------------------------------------------
__global__ __launch_bounds__(256)
void cvt_x_T(const float* __restrict__ X, unsigned short* __restrict__ XT)
{
    __shared__ float L[64][65];
    const int t = threadIdx.x;
    const int n0 = blockIdx.x * 64;
    const int c0 = blockIdx.y * 64;
    const long bofX = (long)blockIdx.z * CC * HWSZ;
    const long bofT = (long)blockIdx.z * HWSZ * CC;
#pragma unroll
    for (int l = 0; l < 4; ++l) {
        int idx = l * 256 + t;
        int ch = idx >> 4, n4 = (idx & 15) * 4;
        float4 v = *(const float4*)&X[bofX + (long)(c0 + ch) * HWSZ + n0 + n4];
        L[n4 + 0][ch] = v.x; L[n4 + 1][ch] = v.y;
        L[n4 + 2][ch] = v.z; L[n4 + 3][ch] = v.w;
    }
    __syncthreads();
#pragma unroll
    for (int l = 0; l < 2; ++l) {
        int idx = l * 256 + t;
        int r = idx >> 3, c8 = (idx & 7) * 8;
        u16x8 o;
#pragma unroll
        for (int e = 0; e < 8; ++e) o[e] = f2bf(L[r][c8 + e]);
        *(u16x8*)&XT[bofT + (long)(n0 + r) * CC + c0 + c8] = o;
    }
}

// ---------------------------------------------------------------------------
// fp32 -> bf16 flat convert (weights). n multiple of 2048; grid n/2048.
// ---------------------------------------------------------------------------
__global__ __launch_bounds__(256)
void cvt_w(const float* __restrict__ A, unsigned short* __restrict__ B)
{
    int i = (blockIdx.x * 256 + threadIdx.x) * 8;
    float4 a = *(const float4*)&A[i];
    float4 b = *(const float4*)&A[i + 4];
    u16x8 o;
    o[0] = f2bf(a.x); o[1] = f2bf(a.y); o[2] = f2bf(a.z); o[3] = f2bf(a.w);
    o[4] = f2bf(b.x); o[5] = f2bf(b.y); o[6] = f2bf(b.z); o[7] = f2bf(b.w);
    *(u16x8*)&B[i] = o;
}

// ---------------------------------------------------------------------------
// MFMA GEMM, m97-style: Y[m][n] = sum_k W[m][k] * X[n][k], K=256.
// ---------------------------------------------------------------------------
__global__ __launch_bounds__(256)
void gemm_mfma2(const unsigned short* __restrict__ Wb,
                const unsigned short* __restrict__ XT,
                void* __restrict__ Yv,
                int MT, long Nn, int mode)
{
    __shared__ __align__(16) unsigned short S[32768];
    const int t = threadIdx.x;
    const int w = t >> 6, lane = t & 63;

    const int nwg = (int)gridDim.x;
    const int bid = (int)blockIdx.x;
    const int q8 = nwg >> 3, r8 = nwg & 7;
    const int xcd = bid & 7, idx = bid >> 3;
    const int sw = (xcd < r8 ? xcd * (q8 + 1) : r8 * (q8 + 1) + (xcd - r8) * q8) + idx;
    const int mt = sw % MT, nt = sw / MT;
    const int m0 = mt * 128;
    const long n0 = (long)nt * 128;

    const int rl  = lane >> 3;
    const int gsw = ((lane & 7) ^ rl) << 3;
    const int lr = lane & 15, gq = lane >> 4;
    const int m_off = (w >> 1) * 64, n_off = (w & 1) * 64;

    f32x4 acc[4][4];
#pragma unroll
    for (int i = 0; i < 4; ++i)
#pragma unroll
        for (int j = 0; j < 4; ++j) acc[i][j] = (f32x4){0.f, 0.f, 0.f, 0.f};

    const unsigned short* GA = Wb + (long)m0 * 256;
    const unsigned short* GB = XT + n0 * 256;

#define STAGE(buf, kt)                                                        \
    {                                                                         \
        const unsigned short* L = S + (buf) * 16384;                          \
        const unsigned short* ga = GA + (kt) * 64;                            \
        const unsigned short* gb = GB + (kt) * 64;                            \
        _Pragma("unroll")                                                     \
        for (int qq = 0; qq < 4; ++qq) {                                      \
            int R = w * 32 + qq * 8;                                          \
            gload16(ga + (long)(R + rl) * 256 + gsw, L + R * 64);             \
            gload16(gb + (long)(R + rl) * 256 + gsw, L + 8192 + R * 64);      \
        }                                                                     \
    }

    STAGE(0, 0);
    __syncthreads();
#pragma unroll
    for (int kt = 0; kt < 4; ++kt) {
        if (kt < 3) STAGE((kt + 1) & 1, kt + 1);
        const unsigned short* L = S + (kt & 1) * 16384;
        s16x8 af[4][2], bf[4][2];
#pragma unroll
        for (int i = 0; i < 4; ++i) {
            int r = m_off + i * 16 + lr;
#pragma unroll
            for (int ks = 0; ks < 2; ++ks)
                af[i][ks] = *(const s16x8*)&L[r * 64 + (((gq + ks * 4) ^ (r & 7)) << 3)];
        }
#pragma unroll
        for (int j = 0; j < 4; ++j) {
            int r = n_off + j * 16 + lr;
#pragma unroll
            for (int ks = 0; ks < 2; ++ks)
                bf[j][ks] = *(const s16x8*)&L[8192 + r * 64 + (((gq + ks * 4) ^ (r & 7)) << 3)];
        }
#pragma unroll
        for (int ks = 0; ks < 2; ++ks)
#pragma unroll
            for (int i = 0; i < 4; ++i)
#pragma unroll
                for (int j = 0; j < 4; ++j)
                    acc[i][j] = __builtin_amdgcn_mfma_f32_16x16x32_bf16(
                        af[i][ks], bf[j][ks], acc[i][j], 0, 0, 0);
        __syncthreads();
    }
#undef STAGE

    const int orow = (lane >> 4) * 4, ocol = lane & 15;
    if (mode == 1) {
        unsigned short* Yb = (unsigned short*)Yv;
#pragma unroll
        for (int i = 0; i < 4; ++i)
#pragma unroll
            for (int j = 0; j < 4; ++j) {
                long col = n0 + n_off + j * 16 + ocol;
#pragma unroll
                for (int r = 0; r < 4; ++r)
                    Yb[(long)(m0 + m_off + i * 16 + orow + r) * Nn + col] =
                        f2bf(acc[i][j][r]);
            }
    } else {
        float* Yb = (float*)Yv;
#pragma unroll
        for (int j = 0; j < 4; ++j) {
            long n = n0 + n_off + j * 16 + ocol;
            int z = (int)(n / HWSZ);
            int hw = (int)(n - (long)z * HWSZ);
            float* base = Yb + (long)z * CC * HWSZ + hw;
#pragma unroll
            for (int i = 0; i < 4; ++i)
#pragma unroll
                for (int r = 0; r < 4; ++r)
                    base[(long)(m0 + m_off + i * 16 + orow + r) * HWSZ] = acc[i][j][r];
        }
    }
}

// ---------------------------------------------------------------------------
// Depthwise 3x3, pad 1 — LDS plane kernel, 4 px/thread via float4 row reads.
// ---------------------------------------------------------------------------
__global__ __launch_bounds__(256)
void dwconv3x3(const unsigned short* __restrict__ X,
               const float* __restrict__ Wd,
               unsigned short* __restrict__ Y,
               int b0, long Nn)
{
    __shared__ float P[HWSZ];
    const int ch = blockIdx.x;
    const int z = blockIdx.y;
    const int t = threadIdx.x;
    const unsigned short* xc = X + (long)ch * Nn + (long)z * HWSZ;
#pragma unroll
    for (int l = 0; l < 3; ++l) {
        int q4 = l * 256 + t;
        u16x4 v = *(const u16x4*)&xc[q4 * 4];
        *(float4*)&P[q4 * 4] =
            make_float4(bf2f(v[0]), bf2f(v[1]), bf2f(v[2]), bf2f(v[3]));
    }
    if (t < 16) {
        int q4 = 768 + t;
        u16x4 v = *(const u16x4*)&xc[q4 * 4];
        *(float4*)&P[q4 * 4] =
            make_float4(bf2f(v[0]), bf2f(v[1]), bf2f(v[2]), bf2f(v[3]));
    }
    float w9[9];
#pragma unroll
    for (int q = 0; q < 9; ++q) w9[q] = Wd[ch * 9 + q];
    __syncthreads();

    unsigned short* yc = Y + ((long)(b0 + z) * C3 + ch) * HWSZ;
    const int lane = t & 63;
#pragma unroll
    for (int l = 0; l < 4; ++l) {
        int g4 = l * 256 + t;
        if (g4 < 784) {
            int qi = g4 / 14, qj = g4 - qi * 14;
            float o0 = 0.f, o1 = 0.f, o2 = 0.f, o3 = 0.f;
#pragma unroll
            for (int di = 0; di < 3; ++di) {
                int ii = qi + di - 1;
                if ((unsigned)ii >= HH) continue;
                const float* Pr = &P[ii * WW + qj * 4];
                float4 v = *(const float4*)Pr;
                float lf = __shfl_up(v.w, 1);
                float rt = __shfl_down(v.x, 1);
                if (lane == 0 && qj != 0)   lf = Pr[-1];
                if (lane == 63 && qj != 13) rt = Pr[4];
                if (qj == 0)  lf = 0.f;
                if (qj == 13) rt = 0.f;
                const float wL = w9[di * 3 + 0], wC = w9[di * 3 + 1], wR = w9[di * 3 + 2];
                o0 += wL * lf  + wC * v.x + wR * v.y;
                o1 += wL * v.x + wC * v.y + wR * v.z;
                o2 += wL * v.y + wC * v.z + wR * v.w;
                o3 += wL * v.z + wC * v.w + wR * rt;
            }
            u16x4 ov;
            ov[0] = f2bf(o0); ov[1] = f2bf(o1); ov[2] = f2bf(o2); ov[3] = f2bf(o3);
            *(u16x4*)&yc[g4 * 4] = ov;
        }
    }
}

// ---------------------------------------------------------------------------
// Phase A via MFMA: per (chunk c, h, b), 4 waves; wave covers 7 steps of 16 px.
// A-frag = q rows (lane&31, k-off (lane>>5)*8), B-frag = k rows (same form).
// acc_qk = Q.K^T partial; acc_qq/acc_kk diagonals give sumsq. LDS-atomic
// reduce across the 4 waves into the SLAB layout (attn_finish unchanged).
// grid (7, 8, 16), block 256.
// ---------------------------------------------------------------------------
__global__ __launch_bounds__(256)
void gram_mfma(const unsigned short* __restrict__ dw, float* __restrict__ gram)
{
    __shared__ float Sred[SLAB];
    const int c = blockIdx.x, h = blockIdx.y, b = blockIdx.z;
    const int t = threadIdx.x;
    const int w = t >> 6, lane = t & 63;
    const unsigned short* qb = dw + ((long)b * C3 + h * HD) * HWSZ;
    const unsigned short* kb = dw + ((long)b * C3 + CC + h * HD) * HWSZ;

    for (int l = t; l < SLAB; l += 256) Sred[l] = 0.f;

    const int row = lane & 31;
    const int hi  = lane >> 5;
    const long rbase = (long)row * HWSZ + hi * 8;

    f32x16 aqk, aqq, akk;
#pragma unroll
    for (int i = 0; i < 16; ++i) { aqk[i] = 0.f; aqq[i] = 0.f; akk[i] = 0.f; }

#pragma unroll
    for (int s = 0; s < 7; ++s) {
        int p0 = (c * 28 + w * 7 + s) * 16;
        s16x8 qf = *(const s16x8*)&qb[rbase + p0];
        s16x8 kf = *(const s16x8*)&kb[rbase + p0];
        aqk = __builtin_amdgcn_mfma_f32_32x32x16_bf16(qf, kf, aqk, 0, 0, 0);
        aqq = __builtin_amdgcn_mfma_f32_32x32x16_bf16(qf, qf, aqq, 0, 0, 0);
        akk = __builtin_amdgcn_mfma_f32_32x32x16_bf16(kf, kf, akk, 0, 0, 0);
    }
    __syncthreads();          // Sred zero complete (zero loop precedes this)

#pragma unroll
    for (int r = 0; r < 16; ++r) {
        int rowd = (r & 3) + 8 * (r >> 2) + 4 * hi;
        atomicAdd(&Sred[rowd * 32 + row], aqk[r]);
    }
    // diag(QQ^T)[j] lives in lane {j or j+32} where ((j>>2)&1)==hi, at reg
    // (j&3)|((j>>3)<<2)  [from 32x32 C-layout row=(r&3)+8*(r>>2)+4*hi]
    {
        int dreg = (row & 3) | ((row >> 3) << 2);
        bool has = ((row >> 2) & 1) == hi;
        float qd = has ? aqq[dreg] : 0.f;
        float kd = has ? akk[dreg] : 0.f;
        qd += __shfl_xor(qd, 32);
        kd += __shfl_xor(kd, 32);
        if (hi == 0) {
            atomicAdd(&Sred[1024 + row], qd);
            atomicAdd(&Sred[1056 + row], kd);
        }
    }
    __syncthreads();
    float* slab = gram + (((long)c * BB + b) * HEADS + h) * SLAB;
    for (int l = t; l < SLAB; l += 256) slab[l] = Sred[l];
}

// ---------------------------------------------------------------------------
// Phase B: sum slabs, normalize, temperature, softmax over j. grid (8,16).
// ---------------------------------------------------------------------------
__global__ __launch_bounds__(1024)
void attn_finish(const float* __restrict__ gram,
                 const float* __restrict__ temp,
                 float* __restrict__ attn)
{
    __shared__ float nrm[64];
    const int h = blockIdx.x, b = blockIdx.y;
    const int t = threadIdx.x;
    const long sbase = ((long)b * HEADS + h) * SLAB;
    const long cstr  = (long)BB * HEADS * SLAB;
    if (t < 64) {
        float s = 0.f;
#pragma unroll
        for (int c = 0; c < NCHUNK; ++c) s += gram[c * cstr + sbase + 1024 + t];
        nrm[t] = fmaxf(sqrtf(s), EPSF);
    }
    __syncthreads();
    const int i = t >> 5, j = t & 31;
    float s = 0.f;
#pragma unroll
    for (int c = 0; c < NCHUNK; ++c) s += gram[c * cstr + sbase + i * 32 + j];
    s *= temp[h] / (nrm[i] * nrm[32 + j]);
    float mx = s;
    mx = fmaxf(mx, __shfl_xor(mx, 1));
    mx = fmaxf(mx, __shfl_xor(mx, 2));
    mx = fmaxf(mx, __shfl_xor(mx, 4));
    mx = fmaxf(mx, __shfl_xor(mx, 8));
    mx = fmaxf(mx, __shfl_xor(mx, 16));
    float e = expf(s - mx);
    float sum = e;
    sum += __shfl_xor(sum, 1); sum += __shfl_xor(sum, 2);
    sum += __shfl_xor(sum, 4); sum += __shfl_xor(sum, 8);
    sum += __shfl_xor(sum, 16);
    attn[(((long)b * HEADS + h) * HD + i) * HD + j] = e / sum;
}

// ---------------------------------------------------------------------------
// out[b, p, h*32+i] (bf16, n-major) = sum_j attn * v[b,h,j,p].
// 2 px per thread (ushort2 loads), j unrolled x4 for load ILP.
// grid (7, 8, 16), block 256.
// ---------------------------------------------------------------------------
__global__ __launch_bounds__(256)
void attn_apply(const unsigned short* __restrict__ dw,
                const float* __restrict__ attn,
                unsigned short* __restrict__ obT)
{
    __shared__ float As[HD * HD];
    const int h = blockIdx.y, b = blockIdx.z;
    const int t = threadIdx.x;
    const float* ab = attn + ((long)b * HEADS + h) * HD * HD;
#pragma unroll
    for (int l = 0; l < 4; ++l) As[l * 256 + t] = ab[l * 256 + t];
    __syncthreads();
    const int pp = blockIdx.x * 256 + t;
    if (pp >= HWSZ / 2) return;
    const int p = pp * 2;
    const unsigned short* vb = dw + ((long)b * C3 + 2 * CC + h * HD) * HWSZ + p;
    float acc0[32], acc1[32];
#pragma unroll
    for (int i = 0; i < 32; ++i) { acc0[i] = 0.f; acc1[i] = 0.f; }
#pragma unroll 4
    for (int j = 0; j < 32; ++j) {
        ushort2 vv = *(const ushort2*)&vb[(long)j * HWSZ];
        float v0 = bf2f(vv.x), v1 = bf2f(vv.y);
#pragma unroll
        for (int i = 0; i < 32; ++i) {
            float a = As[i * 32 + j];
            acc0[i] += a * v0;
            acc1[i] += a * v1;
        }
    }
    unsigned short* ob = obT + (long)b * HWSZ * CC + (long)p * CC + h * HD;
#pragma unroll
    for (int g = 0; g < 4; ++g) {
        u16x8 o0, o1;
#pragma unroll
        for (int e = 0; e < 8; ++e) {
            o0[e] = f2bf(acc0[g * 8 + e]);
            o1[e] = f2bf(acc1[g * 8 + e]);
        }
        *(u16x8*)&ob[g * 8] = o0;
        *(u16x8*)&ob[CC + g * 8] = o1;
    }
}

// ---------------------------------------------------------------------------
extern "C" void kernel_launch(void* const* d_in, const int* in_sizes, int n_in,
                              void* d_out, int out_size, void* d_ws, size_t ws_size,
                              hipStream_t stream)
{
    const float* x      = (const float*)d_in[0];
    const float* w_qkv  = (const float*)d_in[1];
    const float* w_dw   = (const float*)d_in[2];
    const float* w_proj = (const float*)d_in[3];
    const float* temp   = (const float*)d_in[4];
    float* out = (float*)d_out;
    float* ws  = (float*)d_ws;

    const size_t atF = (size_t)BB * HEADS * HD * HD;           // 131,072 f
    const size_t grF = (size_t)NCHUNK * BB * HEADS * SLAB;     // 974,848 f
    const size_t dwE = (size_t)BB * C3 * HWSZ;                 // u16
    const size_t xbE = (size_t)BB * HWSZ * CC;                 // u16
    const size_t pbFh = (size_t)C3 * HWSZ / 2;                 // tmp bf16 per batch, floats

    float* at   = ws;
    float* gram = ws + atF;
    unsigned short* dw16 = (unsigned short*)(ws + atF + grF);
    unsigned short* xbT  = dw16 + dwE;
    unsigned short* obT  = xbT + xbE;
    unsigned short* wqb  = obT + xbE;
    unsigned short* wpb  = wqb + (size_t)C3 * CC;
    size_t baseF = atF + grF +
        (dwE + 2 * xbE + (size_t)C3 * CC + (size_t)CC * CC + 1) / 2;
    baseF = (baseF + 3) & ~(size_t)3;
    unsigned short* tmp = (unsigned short*)(ws + baseF);

    long availF = (long)(ws_size / 4) - (long)baseF;
    long gl = availF / (long)pbFh;
    if (gl > BB) gl = BB;
    gl &= ~1L;
    if (gl < 2) gl = 2;
    const int g = (int)gl;

    cvt_x_T<<<dim3(49, 4, BB), 256, 0, stream>>>(x, xbT);
    cvt_w<<<dim3((C3 * CC) / 2048), 256, 0, stream>>>(w_qkv, wqb);
    cvt_w<<<dim3((CC * CC) / 2048), 256, 0, stream>>>(w_proj, wpb);

    for (int b0 = 0; b0 < BB; b0 += g) {
        int gc = g < (BB - b0) ? g : (BB - b0);
        long Ng = (long)gc * HWSZ;
        int nwg = 6 * (int)(Ng / 128);
        gemm_mfma2<<<dim3(nwg), 256, 0, stream>>>(
            wqb, xbT + (size_t)b0 * HWSZ * CC, tmp, 6, Ng, 1);
        dwconv3x3<<<dim3(C3, gc), 256, 0, stream>>>(tmp, w_dw, dw16, b0, Ng);
    }
    gram_mfma<<<dim3(NCHUNK, HEADS, BB), 256, 0, stream>>>(dw16, gram);
    attn_finish<<<dim3(HEADS, BB), 1024, 0, stream>>>(gram, temp, at);
    attn_apply<<<dim3(7, HEADS, BB), 256, 0, stream>>>(dw16, at, obT);
    {
        long Nn = (long)BB * HWSZ;               // 50176
        int nwg = 2 * (int)(Nn / 128);           // 784
        gemm_mfma2<<<dim3(nwg), 256, 0, stream>>>(
            wpb, obT, out, 2, Nn, 0);
    }
}

// Round 9
// 164.005 us; speedup vs baseline: 5.0549x; 1.0594x over previous
//
#include <hip/hip_runtime.h>
#include <math.h>

#define BB 16
#define CC 256
#define C3 768
#define HH 56
#define WW 56
#define HWSZ 3136
#define HEADS 8
#define HD 32
#define EPSF 1e-12f
#define NCHUNK 7
#define SLAB 1088             // 32*32 gram + 32 q-sumsq + 32 k-sumsq

using s16x8 = __attribute__((ext_vector_type(8))) short;
using u16x8 = __attribute__((ext_vector_type(8))) unsigned short;
using u16x4 = __attribute__((ext_vector_type(4))) unsigned short;
using f32x4 = __attribute__((ext_vector_type(4))) float;
using f32x16 = __attribute__((ext_vector_type(16))) float;

__device__ inline unsigned short f2bf(float f) {
    unsigned int u = __float_as_uint(f);
    return (unsigned short)((u + 0x7FFFu + ((u >> 16) & 1u)) >> 16);
}
__device__ inline float bf2f(unsigned short s) {
    return __uint_as_float((unsigned int)s << 16);
}
__device__ inline void gload16(const unsigned short* g, const unsigned short* l) {
    __builtin_amdgcn_global_load_lds(
        (const __attribute__((address_space(1))) void*)g,
        (__attribute__((address_space(3))) void*)l, 16, 0, 0);
}

// ---------------------------------------------------------------------------
// fp32 -> bf16 flat convert (qkv weights). n multiple of 2048; grid n/2048.
// ---------------------------------------------------------------------------
__global__ __launch_bounds__(256)
void cvt_w(const float* __restrict__ A, unsigned short* __restrict__ B)
{
    int i = (blockIdx.x * 256 + threadIdx.x) * 8;
    float4 a = *(const float4*)&A[i];
    float4 b = *(const float4*)&A[i + 4];
    u16x8 o;
    o[0] = f2bf(a.x); o[1] = f2bf(a.y); o[2] = f2bf(a.z); o[3] = f2bf(a.w);
    o[4] = f2bf(b.x); o[5] = f2bf(b.y); o[6] = f2bf(b.z); o[7] = f2bf(b.w);
    *(u16x8*)&B[i] = o;
}

// ---------------------------------------------------------------------------
// GEMM with in-kernel B-transpose: Y[m][n] = sum_k A[m][k] * B[k][n].
// A bf16 [M][256] row-major (gload16, linear LDS, source-XOR swizzle).
// B staged from k-major source: coalesced loads -> regs -> bf16 ->
// XOR-swizzled ds_write_b64 into LDS [128n][64k].
// MODE 0: B = x fp32 [b][256][3136], n global (z = n/3136); Y = tmp bf16
//         [768][50176]; MT=6, grid 1-D 2352.
// MODE 1: B = v bf16 rows of dw16 (per z); A = M[z]; Y = out fp32
//         [z][256][3136]; MT=2, grid (50, 16), tail tile guarded.
// ---------------------------------------------------------------------------
template<int MODE>
__global__ __launch_bounds__(256)
void gemm_tb(const unsigned short* __restrict__ Ab,
             const void* __restrict__ Bv,
             void* __restrict__ Yv)
{
    constexpr int MT = (MODE == 0) ? 6 : 2;
    __shared__ __align__(16) unsigned short S[32768];   // 2 x (A 16KB + B 16KB)
    const int t = threadIdx.x;
    const int w = t >> 6, lane = t & 63;

    const int nwg = (int)gridDim.x;
    const int bid = (int)blockIdx.x;
    const int q8 = nwg >> 3, r8 = nwg & 7;
    const int xcd = bid & 7, idx = bid >> 3;
    const int sw = (xcd < r8 ? xcd * (q8 + 1) : r8 * (q8 + 1) + (xcd - r8) * q8) + idx;
    const int mt = sw % MT, nt = sw / MT;
    const int m0 = mt * 128;
    const int n0 = nt * 128;
    const int z = (MODE == 1) ? (int)blockIdx.y : 0;

    // A staging (gload16): 8 rows per inst, source granule XOR
    const int rl  = lane >> 3;
    const int gsw = ((lane & 7) ^ rl) << 3;
    // fragment addressing
    const int lr = lane & 15, gq = lane >> 4;
    const int m_off = (w >> 1) * 64, n_off = (w & 1) * 64;

    // B staging: thread (nq, kr): 8 rows k = kr*8+l, float4/u16x4 of 4 n
    const int nq = t & 31, kr = t >> 5;
    const int nrow = nq * 4;
    long bz; int hw;
    if (MODE == 0) {
        int ng = n0 + nrow;
        int z0 = ng / HWSZ;
        hw = ng - z0 * HWSZ;
        bz = (long)z0 * CC * HWSZ;
    } else {
        hw = n0 + nrow;
        if (hw > HWSZ - 4) hw = HWSZ - 4;
        bz = ((long)z * C3 + 2 * CC) * HWSZ;
    }

    const unsigned short* GA = Ab + ((MODE == 1) ? (long)z * CC * CC : 0)
                                  + (long)m0 * 256;

    f32x4 acc[4][4];
#pragma unroll
    for (int i = 0; i < 4; ++i)
#pragma unroll
        for (int j = 0; j < 4; ++j) acc[i][j] = (f32x4){0.f, 0.f, 0.f, 0.f};

    u16x4 stg[8];

#define LOADB(kt)                                                             \
    {                                                                         \
        if (MODE == 0) {                                                      \
            const float* Bf = (const float*)Bv + bz + hw;                     \
            _Pragma("unroll")                                                 \
            for (int l = 0; l < 8; ++l) {                                     \
                float4 v = *(const float4*)(Bf + (long)((kt) * 64 + kr * 8 + l) * HWSZ); \
                u16x4 o; o[0] = f2bf(v.x); o[1] = f2bf(v.y);                  \
                o[2] = f2bf(v.z); o[3] = f2bf(v.w);                           \
                stg[l] = o;                                                   \
            }                                                                 \
        } else {                                                              \
            const unsigned short* Bu = (const unsigned short*)Bv + bz + hw;   \
            _Pragma("unroll")                                                 \
            for (int l = 0; l < 8; ++l)                                       \
                stg[l] = *(const u16x4*)(Bu + (long)((kt) * 64 + kr * 8 + l) * HWSZ); \
        }                                                                     \
    }

#define WRITEB(buf)                                                           \
    {                                                                         \
        unsigned short* LB = S + (buf) * 16384 + 8192;                        \
        _Pragma("unroll")                                                     \
        for (int e = 0; e < 4; ++e) {                                         \
            int n = nrow + e;                                                 \
            int ro = n * 64 + ((kr ^ (n & 7)) << 3);                          \
            u16x4 lo, hi;                                                     \
            lo[0] = stg[0][e]; lo[1] = stg[1][e];                             \
            lo[2] = stg[2][e]; lo[3] = stg[3][e];                             \
            hi[0] = stg[4][e]; hi[1] = stg[5][e];                             \
            hi[2] = stg[6][e]; hi[3] = stg[7][e];                             \
            *(u16x4*)&LB[ro] = lo;                                            \
            *(u16x4*)&LB[ro + 4] = hi;                                        \
        }                                                                     \
    }

#define STAGEA(buf, kt)                                                       \
    {                                                                         \
        const unsigned short* LA = S + (buf) * 16384;                         \
        const unsigned short* ga = GA + (kt) * 64;                            \
        _Pragma("unroll")                                                     \
        for (int qq = 0; qq < 4; ++qq) {                                      \
            int R = w * 32 + qq * 8;                                          \
            gload16(ga + (long)(R + rl) * 256 + gsw, LA + R * 64);            \
        }                                                                     \
    }

    LOADB(0);
    STAGEA(0, 0);
    WRITEB(0);
    __syncthreads();

#pragma unroll
    for (int kt = 0; kt < 4; ++kt) {
        const int cur = kt & 1;
        if (kt < 3) { LOADB(kt + 1); STAGEA(cur ^ 1, kt + 1); }
        {
            const unsigned short* LA = S + cur * 16384;
            const unsigned short* LB = S + cur * 16384 + 8192;
            s16x8 af[4][2], bf[4][2];
#pragma unroll
            for (int i = 0; i < 4; ++i) {
                int r = m_off + i * 16 + lr;
#pragma unroll
                for (int ks = 0; ks < 2; ++ks)
                    af[i][ks] = *(const s16x8*)&LA[r * 64 + (((gq + ks * 4) ^ (r & 7)) << 3)];
            }
#pragma unroll
            for (int j = 0; j < 4; ++j) {
                int r = n_off + j * 16 + lr;
#pragma unroll
                for (int ks = 0; ks < 2; ++ks)
                    bf[j][ks] = *(const s16x8*)&LB[r * 64 + (((gq + ks * 4) ^ (r & 7)) << 3)];
            }
#pragma unroll
            for (int ks = 0; ks < 2; ++ks)
#pragma unroll
                for (int i = 0; i < 4; ++i)
#pragma unroll
                    for (int j = 0; j < 4; ++j)
                        acc[i][j] = __builtin_amdgcn_mfma_f32_16x16x32_bf16(
                            af[i][ks], bf[j][ks], acc[i][j], 0, 0, 0);
        }
        __syncthreads();
        if (kt < 3) WRITEB(cur ^ 1);
        __syncthreads();
    }
#undef LOADB
#undef WRITEB
#undef STAGEA

    const int orow = (lane >> 4) * 4, ocol = lane & 15;
    if (MODE == 0) {
        unsigned short* Yb = (unsigned short*)Yv;
        const long Nn = (long)BB * HWSZ;
#pragma unroll
        for (int i = 0; i < 4; ++i)
#pragma unroll
            for (int j = 0; j < 4; ++j) {
                long col = n0 + n_off + j * 16 + ocol;
#pragma unroll
                for (int r = 0; r < 4; ++r)
                    Yb[(long)(m0 + m_off + i * 16 + orow + r) * Nn + col] =
                        f2bf(acc[i][j][r]);
            }
    } else {
        float* Yb = (float*)Yv + (long)z * CC * HWSZ;
#pragma unroll
        for (int j = 0; j < 4; ++j) {
            int col = n0 + n_off + j * 16 + ocol;
            if (col < HWSZ) {
#pragma unroll
                for (int i = 0; i < 4; ++i)
#pragma unroll
                    for (int r = 0; r < 4; ++r)
                        Yb[(long)(m0 + m_off + i * 16 + orow + r) * HWSZ + col] =
                            acc[i][j][r];
            }
        }
    }
}

// ---------------------------------------------------------------------------
// Depthwise 3x3, pad 1 — LDS plane kernel, 4 px/thread via float4 row reads.
// ---------------------------------------------------------------------------
__global__ __launch_bounds__(256)
void dwconv3x3(const unsigned short* __restrict__ X,
               const float* __restrict__ Wd,
               unsigned short* __restrict__ Y,
               long Nn)
{
    __shared__ float P[HWSZ];
    const int ch = blockIdx.x;
    const int z = blockIdx.y;
    const int t = threadIdx.x;
    const unsigned short* xc = X + (long)ch * Nn + (long)z * HWSZ;
#pragma unroll
    for (int l = 0; l < 3; ++l) {
        int q4 = l * 256 + t;
        u16x4 v = *(const u16x4*)&xc[q4 * 4];
        *(float4*)&P[q4 * 4] =
            make_float4(bf2f(v[0]), bf2f(v[1]), bf2f(v[2]), bf2f(v[3]));
    }
    if (t < 16) {
        int q4 = 768 + t;
        u16x4 v = *(const u16x4*)&xc[q4 * 4];
        *(float4*)&P[q4 * 4] =
            make_float4(bf2f(v[0]), bf2f(v[1]), bf2f(v[2]), bf2f(v[3]));
    }
    float w9[9];
#pragma unroll
    for (int q = 0; q < 9; ++q) w9[q] = Wd[ch * 9 + q];
    __syncthreads();

    unsigned short* yc = Y + ((long)z * C3 + ch) * HWSZ;
    const int lane = t & 63;
#pragma unroll
    for (int l = 0; l < 4; ++l) {
        int g4 = l * 256 + t;
        if (g4 < 784) {
            int qi = g4 / 14, qj = g4 - qi * 14;
            float o0 = 0.f, o1 = 0.f, o2 = 0.f, o3 = 0.f;
#pragma unroll
            for (int di = 0; di < 3; ++di) {
                int ii = qi + di - 1;
                if ((unsigned)ii >= HH) continue;
                const float* Pr = &P[ii * WW + qj * 4];
                float4 v = *(const float4*)Pr;
                float lf = __shfl_up(v.w, 1);
                float rt = __shfl_down(v.x, 1);
                if (lane == 0 && qj != 0)   lf = Pr[-1];
                if (lane == 63 && qj != 13) rt = Pr[4];
                if (qj == 0)  lf = 0.f;
                if (qj == 13) rt = 0.f;
                const float wL = w9[di * 3 + 0], wC = w9[di * 3 + 1], wR = w9[di * 3 + 2];
                o0 += wL * lf  + wC * v.x + wR * v.y;
                o1 += wL * v.x + wC * v.y + wR * v.z;
                o2 += wL * v.y + wC * v.z + wR * v.w;
                o3 += wL * v.z + wC * v.w + wR * rt;
            }
            u16x4 ov;
            ov[0] = f2bf(o0); ov[1] = f2bf(o1); ov[2] = f2bf(o2); ov[3] = f2bf(o3);
            *(u16x4*)&yc[g4 * 4] = ov;
        }
    }
}

// ---------------------------------------------------------------------------
// Gram via MFMA: partial Q.K^T + diag norms per (chunk, h, b). grid (7,8,16).
// ---------------------------------------------------------------------------
__global__ __launch_bounds__(256)
void gram_mfma(const unsigned short* __restrict__ dw, float* __restrict__ gram)
{
    __shared__ float Sred[SLAB];
    const int c = blockIdx.x, h = blockIdx.y, b = blockIdx.z;
    const int t = threadIdx.x;
    const int w = t >> 6, lane = t & 63;
    const unsigned short* qb = dw + ((long)b * C3 + h * HD) * HWSZ;
    const unsigned short* kb = dw + ((long)b * C3 + CC + h * HD) * HWSZ;

    for (int l = t; l < SLAB; l += 256) Sred[l] = 0.f;

    const int row = lane & 31;
    const int hi  = lane >> 5;
    const long rbase = (long)row * HWSZ + hi * 8;

    f32x16 aqk, aqq, akk;
#pragma unroll
    for (int i = 0; i < 16; ++i) { aqk[i] = 0.f; aqq[i] = 0.f; akk[i] = 0.f; }

#pragma unroll
    for (int s = 0; s < 7; ++s) {
        int p0 = (c * 28 + w * 7 + s) * 16;
        s16x8 qf = *(const s16x8*)&qb[rbase + p0];
        s16x8 kf = *(const s16x8*)&kb[rbase + p0];
        aqk = __builtin_amdgcn_mfma_f32_32x32x16_bf16(qf, kf, aqk, 0, 0, 0);
        aqq = __builtin_amdgcn_mfma_f32_32x32x16_bf16(qf, qf, aqq, 0, 0, 0);
        akk = __builtin_amdgcn_mfma_f32_32x32x16_bf16(kf, kf, akk, 0, 0, 0);
    }
    __syncthreads();

#pragma unroll
    for (int r = 0; r < 16; ++r) {
        int rowd = (r & 3) + 8 * (r >> 2) + 4 * hi;
        atomicAdd(&Sred[rowd * 32 + row], aqk[r]);
    }
    {
        int dreg = (row & 3) | ((row >> 3) << 2);
        bool has = ((row >> 2) & 1) == hi;
        float qd = has ? aqq[dreg] : 0.f;
        float kd = has ? akk[dreg] : 0.f;
        qd += __shfl_xor(qd, 32);
        kd += __shfl_xor(kd, 32);
        if (hi == 0) {
            atomicAdd(&Sred[1024 + row], qd);
            atomicAdd(&Sred[1056 + row], kd);
        }
    }
    __syncthreads();
    float* slab = gram + (((long)c * BB + b) * HEADS + h) * SLAB;
    for (int l = t; l < SLAB; l += 256) slab[l] = Sred[l];
}

// ---------------------------------------------------------------------------
// Sum slabs, normalize, temperature, softmax over j; write TRANSPOSED
// attn: atT[b][h][j][i] (fp32) for the mprep MFMA B-operand. grid (8,16).
// ---------------------------------------------------------------------------
__global__ __launch_bounds__(1024)
void attn_finish(const float* __restrict__ gram,
                 const float* __restrict__ temp,
                 float* __restrict__ attnT)
{
    __shared__ float nrm[64];
    const int h = blockIdx.x, b = blockIdx.y;
    const int t = threadIdx.x;
    const long sbase = ((long)b * HEADS + h) * SLAB;
    const long cstr  = (long)BB * HEADS * SLAB;
    if (t < 64) {
        float s = 0.f;
#pragma unroll
        for (int c = 0; c < NCHUNK; ++c) s += gram[c * cstr + sbase + 1024 + t];
        nrm[t] = fmaxf(sqrtf(s), EPSF);
    }
    __syncthreads();
    const int i = t >> 5, j = t & 31;
    float s = 0.f;
#pragma unroll
    for (int c = 0; c < NCHUNK; ++c) s += gram[c * cstr + sbase + i * 32 + j];
    s *= temp[h] / (nrm[i] * nrm[32 + j]);
    float mx = s;
    mx = fmaxf(mx, __shfl_xor(mx, 1));
    mx = fmaxf(mx, __shfl_xor(mx, 2));
    mx = fmaxf(mx, __shfl_xor(mx, 4));
    mx = fmaxf(mx, __shfl_xor(mx, 8));
    mx = fmaxf(mx, __shfl_xor(mx, 16));
    float e = expf(s - mx);
    float sum = e;
    sum += __shfl_xor(sum, 1); sum += __shfl_xor(sum, 2);
    sum += __shfl_xor(sum, 4); sum += __shfl_xor(sum, 8);
    sum += __shfl_xor(sum, 16);
    attnT[(((long)b * HEADS + h) * HD + j) * HD + i] = e / sum;
}

// ---------------------------------------------------------------------------
// M[b] = Wp x blockdiag(attn): M[m][h*32+j] = sum_i Wp[m][h*32+i]*at[h][i][j].
// MFMA 16x16x32 per (h, m16, j16): A = Wp rows (fp32->bf16), B = atT rows.
// grid (16 b), block 256 (4 waves, wave w -> m 64w..64w+63). Output bf16.
// ---------------------------------------------------------------------------
__global__ __launch_bounds__(256)
void mprep(const float* __restrict__ Wp,
           const float* __restrict__ atT,
           unsigned short* __restrict__ Mm)
{
    const int zb = blockIdx.x;
    const int t = threadIdx.x, w = t >> 6, lane = t & 63;
    const int lr = lane & 15, gq = lane >> 4;
    const int m_base = w * 64;
    const float* atb = atT + (long)zb * HEADS * HD * HD;
    unsigned short* Mb = Mm + (long)zb * CC * CC;

#pragma unroll
    for (int h = 0; h < 8; ++h) {
        s16x8 bf[2];
#pragma unroll
        for (int jt = 0; jt < 2; ++jt) {
            const float* src = atb + (long)(h * 32 + jt * 16 + lr) * 32 + gq * 8;
            float4 a = *(const float4*)src;
            float4 b = *(const float4*)(src + 4);
            s16x8 v;
            v[0] = (short)f2bf(a.x); v[1] = (short)f2bf(a.y);
            v[2] = (short)f2bf(a.z); v[3] = (short)f2bf(a.w);
            v[4] = (short)f2bf(b.x); v[5] = (short)f2bf(b.y);
            v[6] = (short)f2bf(b.z); v[7] = (short)f2bf(b.w);
            bf[jt] = v;
        }
#pragma unroll
        for (int i = 0; i < 4; ++i) {
            const float* src = Wp + (long)(m_base + i * 16 + lr) * 256 + h * 32 + gq * 8;
            float4 a = *(const float4*)src;
            float4 b = *(const float4*)(src + 4);
            s16x8 af;
            af[0] = (short)f2bf(a.x); af[1] = (short)f2bf(a.y);
            af[2] = (short)f2bf(a.z); af[3] = (short)f2bf(a.w);
            af[4] = (short)f2bf(b.x); af[5] = (short)f2bf(b.y);
            af[6] = (short)f2bf(b.z); af[7] = (short)f2bf(b.w);
#pragma unroll
            for (int jt = 0; jt < 2; ++jt) {
                f32x4 acc = (f32x4){0.f, 0.f, 0.f, 0.f};
                acc = __builtin_amdgcn_mfma_f32_16x16x32_bf16(af, bf[jt], acc, 0, 0, 0);
#pragma unroll
                for (int r = 0; r < 4; ++r)
                    Mb[(long)(m_base + i * 16 + gq * 4 + r) * 256
                       + h * 32 + jt * 16 + lr] = f2bf(acc[r]);
            }
        }
    }
}

// ---------------------------------------------------------------------------
extern "C" void kernel_launch(void* const* d_in, const int* in_sizes, int n_in,
                              void* d_out, int out_size, void* d_ws, size_t ws_size,
                              hipStream_t stream)
{
    const float* x      = (const float*)d_in[0];
    const float* w_qkv  = (const float*)d_in[1];
    const float* w_dw   = (const float*)d_in[2];
    const float* w_proj = (const float*)d_in[3];
    const float* temp   = (const float*)d_in[4];
    float* out = (float*)d_out;
    float* ws  = (float*)d_ws;

    const size_t atF = (size_t)BB * HEADS * HD * HD;           // 131,072 f
    const size_t grF = (size_t)NCHUNK * BB * HEADS * SLAB;     // 974,848 f
    const size_t dwE = (size_t)BB * C3 * HWSZ;                 // u16
    const size_t wqE = (size_t)C3 * CC;                        // u16
    const size_t mmE = (size_t)BB * CC * CC;                   // u16

    float* atT  = ws;
    float* gram = ws + atF;
    unsigned short* dw16 = (unsigned short*)(ws + atF + grF);
    unsigned short* wqb  = dw16 + dwE;
    unsigned short* Mm   = wqb + wqE;
    unsigned short* tmp  = Mm + mmE;
    // total ~161 MB < ws (268 MB observed)

    cvt_w<<<dim3((C3 * CC) / 2048), 256, 0, stream>>>(w_qkv, wqb);

    // qkv: [768 x 50176 x 256], B = x transposed in-kernel. 6*392 = 2352 wgs.
    gemm_tb<0><<<dim3(2352), 256, 0, stream>>>(wqb, x, tmp);

    dwconv3x3<<<dim3(C3, BB), 256, 0, stream>>>(tmp, w_dw, dw16, (long)BB * HWSZ);

    gram_mfma<<<dim3(NCHUNK, HEADS, BB), 256, 0, stream>>>(dw16, gram);
    attn_finish<<<dim3(HEADS, BB), 1024, 0, stream>>>(gram, temp, atT);
    mprep<<<dim3(BB), 256, 0, stream>>>(w_proj, atT, Mm);

    // proj: per-z [256 x 3136 x 256], A = M[z], B = v rows of dw16.
    gemm_tb<1><<<dim3(50, BB), 256, 0, stream>>>(Mm, dw16, out);
}